// Round 9
// baseline (786.109 us; speedup 1.0000x reference)
//
#include <hip/hip_runtime.h>
#include <hip/hip_fp16.h>

#define NN 100000
#define NE 1200000
#define DD 64
#define EDIM 16
#define NL 3
#define NG 512
#define NC 10
#define NB_SCAN ((NN + 255) / 256)   // 391
#define NBLK (NN / 32)               // 3125 fused blocks (32 nodes, 2 waves each)

typedef _Float16 f16x2 __attribute__((ext_vector_type(2)));
typedef _Float16 v8h   __attribute__((ext_vector_type(8)));
typedef float    v4f   __attribute__((ext_vector_type(4)));

__device__ __forceinline__ unsigned packh2(float a, float b) {
    f16x2 v; v[0] = (_Float16)a; v[1] = (_Float16)b;
    unsigned u; __builtin_memcpy(&u, &v, 4); return u;
}
__device__ __forceinline__ float dot2f(unsigned a, unsigned b, float c) {
    f16x2 av, bv;
    __builtin_memcpy(&av, &a, 4); __builtin_memcpy(&bv, &b, 4);
#if __has_builtin(__builtin_amdgcn_fdot2)
    return __builtin_amdgcn_fdot2(av, bv, c, false);
#else
    return c + (float)av[0]*(float)bv[0] + (float)av[1]*(float)bv[1];
#endif
}

// inline BN: scale/shift from raw sums (same math as bn_finalize incl. one
// Newton step on rsqrt -> bit-identical results, kernel fused away)
__device__ __forceinline__ void bn_sc_sh(float s, float q, float g, float b,
                                         float invc, float& sc, float& sh) {
    float mu  = s * invc;
    float var = fmaxf(q * invc - mu * mu, 0.f);
    float x = var + 1e-5f;
    float r = rsqrtf(x);
    r = r * (1.5f - 0.5f * x * r * r);
    sc = g * r;
    sh = b - mu * sc;
}

// ---------------------------------------------------------------------------
// prep: Wc[l] = w_edge @ lin_w[l] (16x64) packed to f16 pairs per column;
//       bc[l] = b_edge @ lin_w[l] + lin_b[l]  (fp32)
__global__ __launch_bounds__(1024) void prep_kernel(
    const float* __restrict__ w_edge, const float* __restrict__ b_edge,
    const float* __restrict__ lin_w, const float* __restrict__ lin_b,
    unsigned* __restrict__ Wc16, float* __restrict__ bc)
{
    __shared__ float sWc[1024];
    const int l = blockIdx.x;
    const int tid = threadIdx.x;
    const float* Lw = lin_w + l * 4096;
    const int k = tid >> 6, col = tid & 63;
    float acc = 0.f;
    for (int j = 0; j < 64; ++j) acc = fmaf(w_edge[k*64 + j], Lw[j*64 + col], acc);
    sWc[k*64 + col] = acc;
    if (tid < 64) {
        float a = lin_b[l*64 + tid];
        for (int j = 0; j < 64; ++j) a = fmaf(b_edge[j], Lw[j*64 + tid], a);
        bc[l*64 + tid] = a;
    }
    __syncthreads();
    if (tid < 512) {
        const int j = tid >> 6, c = tid & 63;     // j = pair index (dims 2j,2j+1)
        Wc16[l*512 + j*64 + c] = packh2(sWc[(2*j)*64 + c], sWc[(2*j+1)*64 + c]);
    }
}

// ---------------------------------------------------------------------------
// pack node-GEMM weights [64x64] fp32 -> f16 MFMA B-fragment order.
// m: 0 = w_node, 1..3 = mlp1_w[l], 4..6 = mlp2_w[l]
__global__ __launch_bounds__(512) void pack_w_kernel(
    const float* __restrict__ w_node, const float* __restrict__ mlp1_w,
    const float* __restrict__ mlp2_w, v8h* __restrict__ Wpk)
{
    const int m = blockIdx.x;
    const float* W = (m == 0) ? w_node
                   : (m <= 3) ? mlp1_w + (m-1)*4096
                              : mlp2_w + (m-4)*4096;
    const int fid = threadIdx.x >> 6;
    const int l   = threadIdx.x & 63;
    const int t = fid >> 1, f = fid & 1;
    const int n  = (l & 15) + 16*t;
    const int kb = f*32 + (l >> 4)*8;
    v8h v;
    #pragma unroll
    for (int j = 0; j < 8; ++j) v[j] = (_Float16)W[(kb + j)*64 + n];
    Wpk[m*512 + fid*64 + l] = v;
}

// ---------------------------------------------------------------------------
// CSR build: histogram of dst
__global__ __launch_bounds__(256) void hist_kernel(
    const int* __restrict__ dst, int* __restrict__ counts)
{
    const int e = blockIdx.x * 256 + threadIdx.x;
    if (e < NE) atomicAdd(&counts[dst[e]], 1);
}

__global__ __launch_bounds__(256) void scan_reduce_kernel(
    const int* __restrict__ counts, int* __restrict__ bsum)
{
    __shared__ int sd[256];
    const int t = threadIdx.x;
    const int idx = blockIdx.x * 256 + t;
    sd[t] = (idx < NN) ? counts[idx] : 0;
    __syncthreads();
    for (int off = 128; off > 0; off >>= 1) {
        if (t < off) sd[t] += sd[t + off];
        __syncthreads();
    }
    if (t == 0) bsum[blockIdx.x] = sd[0];
}

__global__ __launch_bounds__(512) void scan_partials_kernel(
    const int* __restrict__ bsum, int* __restrict__ bscan)
{
    __shared__ int sd[512];
    const int t = threadIdx.x;
    sd[t] = (t < NB_SCAN) ? bsum[t] : 0;
    __syncthreads();
    for (int off = 1; off < 512; off <<= 1) {
        int u = (t >= off) ? sd[t - off] : 0;
        __syncthreads();
        sd[t] += u;
        __syncthreads();
    }
    if (t < NB_SCAN) bscan[t] = (t == 0) ? 0 : sd[t - 1];
}

__global__ __launch_bounds__(256) void scan_final_kernel(
    const int* __restrict__ counts, const int* __restrict__ bscan,
    int* __restrict__ rowptr, int* __restrict__ next)
{
    __shared__ int sd[256];
    const int t = threadIdx.x;
    const int idx = blockIdx.x * 256 + t;
    const int v = (idx < NN) ? counts[idx] : 0;
    sd[t] = v;
    __syncthreads();
    for (int off = 1; off < 256; off <<= 1) {
        int u = (t >= off) ? sd[t - off] : 0;
        __syncthreads();
        sd[t] += u;
        __syncthreads();
    }
    const int excl = sd[t] - v + bscan[blockIdx.x];
    if (idx < NN) { rowptr[idx] = excl; next[idx] = excl; }
    if (idx == NN - 1) rowptr[NN] = excl + v;
}

// R2-style single-pass scatter — pinned at the per-edge random-line floor
// (R3: 8B payload still cost 80us; R4: binning loses to atomic serialization
// + cross-XCD partial lines). Pay the 1.2M random lines once, full payload.
__global__ __launch_bounds__(256) void scatter_kernel(
    const int* __restrict__ src, const int* __restrict__ dst,
    const float* __restrict__ edge_attr,
    int* __restrict__ next, int* __restrict__ csr_src, uint4* __restrict__ csr_ea)
{
    const int e = blockIdx.x * 256 + threadIdx.x;
    if (e >= NE) return;
    const float4* q = (const float4*)(edge_attr + (size_t)e * 16);
    float4 a0 = q[0], a1 = q[1], a2 = q[2], a3 = q[3];
    const int pos = atomicAdd(&next[dst[e]], 1);
    csr_src[pos] = src[e];
    uint4 A, B;
    A.x = packh2(a0.x, a0.y); A.y = packh2(a0.z, a0.w);
    A.z = packh2(a1.x, a1.y); A.w = packh2(a1.z, a1.w);
    B.x = packh2(a2.x, a2.y); B.y = packh2(a2.z, a2.w);
    B.z = packh2(a3.x, a3.y); B.w = packh2(a3.z, a3.w);
    csr_ea[(size_t)pos*2 + 0] = A;
    csr_ea[(size_t)pos*2 + 1] = B;
}

// ---------------------------------------------------------------------------
// FUSED agg + mlp1 (R8/R9: 2-wave blocks). R7's 4-wave/64-node version ran
// at 38% occupancy: grid 1563 = 6.1 blocks/CU with ~3 resident on average ->
// 3 waves/SIMD couldn't hide the gather chain (VALUBusy 46%). 32 nodes /
// 2 waves per block -> grid 3125 = 12.2/CU, LDS 9.3KB (16-block ceiling),
// finer tail packing. Per-wave machinery unchanged: chunked LDS-stage of the
// wave's CSR run, group-of-4 with double-buffered h16 gather prefetch, node
// results to LDS tile (single owner, fp32->f16 rounded once), then mlp1 MFMA
// (A = tile + h16 self term) + bias + BN stats + t16 out; no inter-phase
// barrier (waves touch only their own tile rows).
__global__ __launch_bounds__(128) void agg_mlp1_kernel(
    const int* __restrict__ rowptr,
    const int* __restrict__ csr_src, const uint4* __restrict__ csr_ea,
    const unsigned* __restrict__ Wc16, const float* __restrict__ bc,
    const _Float16* __restrict__ h16,
    const v8h* __restrict__ Wpk, const float* __restrict__ bias,
    _Float16* __restrict__ t16,
    float* __restrict__ bn_sum, float* __restrict__ bn_sumsq)
{
    __shared__ int rp[33];
    __shared__ __align__(16) _Float16 tile[2][16*72];  // row stride 144B
    __shared__ __align__(16) uint4 sEA[2][128];        // per-wave ea chunk; BN scratch later
    __shared__ __align__(16) int sSRC[2][64];

    const int tid  = threadIdx.x;
    const int lane = tid & 63;
    const int wv   = tid >> 6;                         // 0..1
    const int n0   = blockIdx.x * 32;

    if (tid < 33) {
        int idx = n0 + tid; if (idx > NN) idx = NN;
        rp[tid] = rowptr[idx];
    }
    // zero own tile region (576 dwords per wave)
    {
        unsigned* tz = (unsigned*)tile[wv];
        #pragma unroll
        for (int i = 0; i < 9; ++i) tz[lane + i*64] = 0u;
    }

    unsigned wq[8];
    #pragma unroll
    for (int j = 0; j < 8; ++j) wq[j] = Wc16[j*64 + lane];
    const float mb = bc[lane];

    __syncthreads();              // rp visible to both waves

    // ---------------- edge phase (per wave, nodes [n0+16w, n0+16w+16)) ----
    const int nwb  = 16 * wv;     // local first node
    const int e0   = rp[nwb];
    const int eEnd = rp[nwb + 16];
    int cur = nwb;                // local node cursor
    int nb  = rp[cur + 1];
    float acc = 0.f;

    uint4*     sEAw  = sEA[wv];
    _Float16*  tileW = tile[wv];

    auto msg = [&](uint4 A, uint4 B, float hv) -> float {
        float m = mb;
        m = dot2f(A.x, wq[0], m); m = dot2f(A.y, wq[1], m);
        m = dot2f(A.z, wq[2], m); m = dot2f(A.w, wq[3], m);
        m = dot2f(B.x, wq[4], m); m = dot2f(B.y, wq[5], m);
        m = dot2f(B.z, wq[6], m); m = dot2f(B.w, wq[7], m);
        return fmaxf(m + hv, 0.f);
    };
    auto adv = [&](int q) {       // finish current node, advance to node of edge q
        tileW[(cur - nwb)*72 + lane] = (_Float16)acc;
        acc = 0.f;
        do { ++cur; } while (rp[cur + 1] <= q);
        nb = rp[cur + 1];
    };
    auto doGroup = [&](const uint4* eg, int p,
                       float hv0, float hv1, float hv2, float hv3) {
        float m0, m1, m2, m3;
        { uint4 A = eg[0], B = eg[1]; m0 = msg(A, B, hv0); }
        { uint4 A = eg[2], B = eg[3]; m1 = msg(A, B, hv1); }
        { uint4 A = eg[4], B = eg[5]; m2 = msg(A, B, hv2); }
        { uint4 A = eg[6], B = eg[7]; m3 = msg(A, B, hv3); }
        if (p + 3 < nb) {                            // wave-uniform fast path
            acc += (m0 + m1) + (m2 + m3);
        } else {
            if (p     >= nb) adv(p);     acc += m0;
            if (p + 1 >= nb) adv(p + 1); acc += m1;
            if (p + 2 >= nb) adv(p + 2); acc += m2;
            if (p + 3 >= nb) adv(p + 3); acc += m3;
        }
    };

    for (int base = e0; base < eEnd; base += 64) {
        const int cnt = min(64, eEnd - base);
        // stage this chunk's ea + src (wave-local, no barrier needed)
        if (lane < 2*cnt)      sEAw[lane]      = csr_ea[(size_t)base*2 + lane];
        if (64 + lane < 2*cnt) sEAw[64 + lane] = csr_ea[(size_t)base*2 + 64 + lane];
        if (lane < cnt)        sSRC[wv][lane]  = csr_src[base + lane];

        const int grpN = cnt >> 2;
        if (grpN) {
            int4 s = *(const int4*)&sSRC[wv][0];
            _Float16 hA0 = h16[(size_t)s.x*64 + lane];
            _Float16 hA1 = h16[(size_t)s.y*64 + lane];
            _Float16 hA2 = h16[(size_t)s.z*64 + lane];
            _Float16 hA3 = h16[(size_t)s.w*64 + lane];
            #pragma unroll 1
            for (int gp = 0; gp < grpN; ++gp) {
                // issue next group's gathers (clamped; redundant on last iter)
                const int gn = (gp + 1 < grpN) ? gp + 1 : gp;
                int4 sn = *(const int4*)&sSRC[wv][gn*4];
                _Float16 hB0 = h16[(size_t)sn.x*64 + lane];
                _Float16 hB1 = h16[(size_t)sn.y*64 + lane];
                _Float16 hB2 = h16[(size_t)sn.z*64 + lane];
                _Float16 hB3 = h16[(size_t)sn.w*64 + lane];
                doGroup(sEAw + gp*8, base + gp*4,
                        (float)hA0, (float)hA1, (float)hA2, (float)hA3);
                hA0 = hB0; hA1 = hB1; hA2 = hB2; hA3 = hB3;
            }
        }
        for (int k = grpN*4; k < cnt; ++k) {         // chunk tail (0-3 edges)
            const int p = base + k;
            const int sv = sSRC[wv][k];
            const float hv = (float)h16[(size_t)sv*64 + lane];
            uint4 A = sEAw[k*2], B = sEAw[k*2 + 1];
            const float m = msg(A, B, hv);
            if (p >= nb) adv(p);
            acc += m;
        }
    }
    if (e0 < eEnd)                                   // final node flush
        tileW[(cur - nwb)*72 + lane] = (_Float16)acc;

    // ---------------- MFMA phase (mlp1) — no barrier: own rows only -------
    const int li = lane & 15, quad = lane >> 4;
    const int rb = n0 + nwb;                         // NN % 16 == 0, always active

    v8h Bf[8];
    #pragma unroll
    for (int i = 0; i < 8; ++i) Bf[i] = Wpk[i*64 + lane];

    v4f accm[4] = {v4f{0,0,0,0}, v4f{0,0,0,0}, v4f{0,0,0,0}, v4f{0,0,0,0}};
    {
        const _Float16* trow = tileW + li*72 + quad*8;
        v8h Af0 = *(const v8h*)(trow);
        v8h Af1 = *(const v8h*)(trow + 32);
        const size_t off = (size_t)(rb + li)*64 + quad*8;
        Af0 += *(const v8h*)(h16 + off);             // self term "+h"
        Af1 += *(const v8h*)(h16 + off + 32);
        #pragma unroll
        for (int t = 0; t < 4; ++t) {
            accm[t] = __builtin_amdgcn_mfma_f32_16x16x32_f16(Af0, Bf[t*2+0], accm[t], 0, 0, 0);
            accm[t] = __builtin_amdgcn_mfma_f32_16x16x32_f16(Af1, Bf[t*2+1], accm[t], 0, 0, 0);
        }
    }

    float ps[4] = {0.f, 0.f, 0.f, 0.f}, pq[4] = {0.f, 0.f, 0.f, 0.f};
    #pragma unroll
    for (int t = 0; t < 4; ++t) {
        const int col = li + 16*t;
        const float bcol = bias[col];
        #pragma unroll
        for (int r = 0; r < 4; ++r) {
            const int row = rb + quad*4 + r;
            float v = accm[t][r] + bcol;
            ps[t] += v; pq[t] += v*v;                // BN stats on fp32 value
            t16[(size_t)row*64 + col] = (_Float16)v;
        }
    }

    // BN partial reduction: sEA[wv] reused as per-wave sS(256f)+sQ(256f)
    float* sSw = (float*)sEA[wv];
    #pragma unroll
    for (int t = 0; t < 4; ++t) {
        sSw[lane*4 + t]       = ps[t];
        sSw[256 + lane*4 + t] = pq[t];
    }
    __syncthreads();
    if (tid < 64) {
        const int t = tid >> 4, li2 = tid & 15;
        float s = 0.f, q = 0.f;
        #pragma unroll
        for (int w = 0; w < 2; ++w) {
            const float* pS = (const float*)sEA[w];
            #pragma unroll
            for (int qd = 0; qd < 4; ++qd) {
                const int idx = (qd*16 + li2)*4 + t;
                s += pS[idx]; q += pS[256 + idx];
            }
        }
        atomicAdd(bn_sum + tid, s);
        atomicAdd(bn_sumsq + tid, q);
    }
}

// ---------------------------------------------------------------------------
// MFMA node GEMM: [NN,64] @ [64,64] + bias.
// IN_MODE 0: A = fp32 raw (in0). IN_MODE 2: A = relu(bn(f16 in16)) with
// scale/shift computed inline from raw BN sums.
// OUT_HALF stores f16; OUT_POOL atomically accumulates relu(v) into
// pooled[batch[row]] (wave-level shfl reduction on the sorted-batch fast path).
template<int IN_MODE, bool OUT_RELU, bool OUT_HALF, bool OUT_POOL>
__global__ __launch_bounds__(256) void mfma_gemm_kernel(
    const float* __restrict__ in0, const _Float16* __restrict__ in16,
    const v8h* __restrict__ Wpk, const float* __restrict__ bias,
    const float* __restrict__ bni_sum, const float* __restrict__ bni_sumsq,
    const float* __restrict__ bni_g, const float* __restrict__ bni_b,
    float bni_invc,
    _Float16* __restrict__ out16,
    const int* __restrict__ batch, float* __restrict__ pooled)
{
    __shared__ float sSc[64], sSh[64];
    const int tid = threadIdx.x;
    const int wv = tid >> 6, l = tid & 63;
    const int li = l & 15, quad = l >> 4;
    const int rb = (blockIdx.x * 4 + wv) * 16;   // row-block base
    const bool active = (rb < NN);               // NN % 16 == 0

    if constexpr (IN_MODE == 2) {
        if (tid < 64)
            bn_sc_sh(bni_sum[tid], bni_sumsq[tid], bni_g[tid], bni_b[tid],
                     bni_invc, sSc[tid], sSh[tid]);
        __syncthreads();
    }

    v8h Bf[8];
    #pragma unroll
    for (int i = 0; i < 8; ++i) Bf[i] = Wpk[i*64 + l];

    v4f acc[4] = {v4f{0,0,0,0}, v4f{0,0,0,0}, v4f{0,0,0,0}, v4f{0,0,0,0}};

    if (active) {
        v8h Af[2];
        if constexpr (IN_MODE == 2) {
            const _Float16* arow = in16 + (size_t)(rb + li)*64 + quad*8;
            v8h r0 = *(const v8h*)(arow);
            v8h r1 = *(const v8h*)(arow + 32);
            v8h a0, a1;
            #pragma unroll
            for (int j = 0; j < 8; ++j) {
                const int k0 = quad*8 + j;
                const int k1 = 32 + quad*8 + j;
                a0[j] = (_Float16)fmaxf(fmaf((float)r0[j], sSc[k0], sSh[k0]), 0.f);
                a1[j] = (_Float16)fmaxf(fmaf((float)r1[j], sSc[k1], sSh[k1]), 0.f);
            }
            Af[0] = a0; Af[1] = a1;
        } else {
            const float* arow = in0 + (size_t)(rb + li)*64 + quad*8;
            #pragma unroll
            for (int f = 0; f < 2; ++f) {
                float4 x0 = *(const float4*)(arow + f*32);
                float4 x1 = *(const float4*)(arow + f*32 + 4);
                v8h a;
                a[0] = (_Float16)x0.x; a[1] = (_Float16)x0.y;
                a[2] = (_Float16)x0.z; a[3] = (_Float16)x0.w;
                a[4] = (_Float16)x1.x; a[5] = (_Float16)x1.y;
                a[6] = (_Float16)x1.z; a[7] = (_Float16)x1.w;
                Af[f] = a;
            }
        }
        #pragma unroll
        for (int t = 0; t < 4; ++t) {
            acc[t] = __builtin_amdgcn_mfma_f32_16x16x32_f16(Af[0], Bf[t*2+0], acc[t], 0, 0, 0);
            acc[t] = __builtin_amdgcn_mfma_f32_16x16x32_f16(Af[1], Bf[t*2+1], acc[t], 0, 0, 0);
        }
    }

    if constexpr (OUT_HALF) {
        if (active) {
            #pragma unroll
            for (int t = 0; t < 4; ++t) {
                const int col = li + 16*t;
                const float bcol = bias[col];
                #pragma unroll
                for (int r = 0; r < 4; ++r) {
                    const int row = rb + quad*4 + r;
                    float v = acc[t][r] + bcol;
                    if constexpr (OUT_RELU) v = fmaxf(v, 0.f);
                    out16[(size_t)row*64 + col] = (_Float16)v;
                }
            }
        }
    }

    if constexpr (OUT_POOL) {
        if (active) {
            const int b0  = batch[rb];
            const int b15 = batch[rb + 15];
            if (b0 == b15) {            // whole wave's 16 rows in one graph
                #pragma unroll
                for (int t = 0; t < 4; ++t) {
                    const int col = li + 16*t;
                    const float bcol = bias[col];
                    float s = 0.f;
                    #pragma unroll
                    for (int r = 0; r < 4; ++r)
                        s += fmaxf(acc[t][r] + bcol, 0.f);
                    s += __shfl_xor(s, 16);
                    s += __shfl_xor(s, 32);
                    if (quad == 0) atomicAdd(&pooled[b0*64 + col], s);
                }
            } else {                    // rare straddling wave: per-row
                #pragma unroll
                for (int t = 0; t < 4; ++t) {
                    const int col = li + 16*t;
                    const float bcol = bias[col];
                    #pragma unroll
                    for (int r = 0; r < 4; ++r) {
                        const int row = rb + quad*4 + r;
                        const float v = fmaxf(acc[t][r] + bcol, 0.f);
                        atomicAdd(&pooled[batch[row]*64 + col], v);
                    }
                }
            }
        }
    }
}

// ---------------------------------------------------------------------------
// small vector GEMM for the 512-row head.
// IN_MODE==2 applies relu(bn(x)) during load; scale/shift inline from raw sums.
template<int IN_MODE, bool OUT_RELU, bool OUT_ACCUM>
__global__ __launch_bounds__(256) void gemm64_kernel(
    const float* __restrict__ in0,
    const float* __restrict__ W, const float* __restrict__ bias,
    const float* __restrict__ bni_sum, const float* __restrict__ bni_sumsq,
    const float* __restrict__ bni_g, const float* __restrict__ bni_b,
    float bni_invc,
    float* __restrict__ out, int nrows,
    float* __restrict__ bn_sum, float* __restrict__ bn_sumsq)
{
    __shared__ __align__(16) float sIn[64*64];
    __shared__ float sRedS[512];
    __shared__ float sRedQ[512];
    __shared__ __align__(16) float sSc[64], sSh[64];
    const int tid = threadIdx.x;
    const int c  = tid & 31;
    const int rg = tid >> 5;
    const int r0 = blockIdx.x * 64;

    if constexpr (IN_MODE == 2) {
        if (tid < 64)
            bn_sc_sh(bni_sum[tid], bni_sumsq[tid], bni_g[tid], bni_b[tid],
                     bni_invc, sSc[tid], sSh[tid]);
        __syncthreads();
    }

    float w0[64], w1[64];
    #pragma unroll
    for (int k = 0; k < 64; ++k) { w0[k] = W[k*64 + c]; w1[k] = W[k*64 + c + 32]; }
    const float b0 = bias[c], b1 = bias[c + 32];

    for (int i = tid; i < 1024; i += 256) {
        const int r  = i >> 4;
        const int c4 = (i & 15) * 4;
        const int gr = r0 + r;
        float4 v = make_float4(0.f, 0.f, 0.f, 0.f);
        if (gr < nrows) {
            v = *(const float4*)(in0 + (size_t)gr*64 + c4);
            if constexpr (IN_MODE == 2) {
                float4 s4 = *(const float4*)(sSc + c4);
                float4 h4 = *(const float4*)(sSh + c4);
                v.x = fmaxf(fmaf(v.x, s4.x, h4.x), 0.f);
                v.y = fmaxf(fmaf(v.y, s4.y, h4.y), 0.f);
                v.z = fmaxf(fmaf(v.z, s4.z, h4.z), 0.f);
                v.w = fmaxf(fmaf(v.w, s4.w, h4.w), 0.f);
            }
        }
        *(float4*)(sIn + r*64 + c4) = v;
    }
    __syncthreads();

    float ps0 = 0.f, psq0 = 0.f, ps1 = 0.f, psq1 = 0.f;
    #pragma unroll
    for (int i = 0; i < 8; ++i) {
        const int r = rg + 8*i;
        float a0 = b0, a1 = b1;
        #pragma unroll
        for (int k = 0; k < 64; k += 4) {
            float4 a = *(const float4*)(sIn + r*64 + k);
            a0 = fmaf(a.x, w0[k+0], a0); a1 = fmaf(a.x, w1[k+0], a1);
            a0 = fmaf(a.y, w0[k+1], a0); a1 = fmaf(a.y, w1[k+1], a1);
            a0 = fmaf(a.z, w0[k+2], a0); a1 = fmaf(a.z, w1[k+2], a1);
            a0 = fmaf(a.w, w0[k+3], a0); a1 = fmaf(a.w, w1[k+3], a1);
        }
        const int gr = r0 + r;
        if (gr < nrows) {
            if constexpr (OUT_ACCUM) {
                ps0 += a0; psq0 += a0*a0;
                ps1 += a1; psq1 += a1*a1;
            }
            out[(size_t)gr*64 + c]      = OUT_RELU ? fmaxf(a0, 0.f) : a0;
            out[(size_t)gr*64 + c + 32] = OUT_RELU ? fmaxf(a1, 0.f) : a1;
        }
    }

    if constexpr (OUT_ACCUM) {
        sRedS[rg*64 + c]      = ps0;
        sRedS[rg*64 + c + 32] = ps1;
        sRedQ[rg*64 + c]      = psq0;
        sRedQ[rg*64 + c + 32] = psq1;
        __syncthreads();
        if (tid < 64) {
            float s = 0.f, q = 0.f;
            #pragma unroll
            for (int g = 0; g < 8; ++g) { s += sRedS[g*64 + tid]; q += sRedQ[g*64 + tid]; }
            atomicAdd(bn_sum + tid, s);
            atomicAdd(bn_sumsq + tid, q);
        }
    }
}

// ---------------------------------------------------------------------------
// final head: out = bn(hb) @ fo3_w + fo3_b, BN inline from raw sums
__global__ __launch_bounds__(256) void head_final_kernel(
    const float* __restrict__ hb,
    const float* __restrict__ bni_sum, const float* __restrict__ bni_sumsq,
    const float* __restrict__ bni_g, const float* __restrict__ bni_b,
    float bni_invc,
    const float* __restrict__ fo3_w, const float* __restrict__ fo3_b,
    float* __restrict__ out)
{
    __shared__ float sSc[64], sSh[64];
    const int tid = threadIdx.x;
    if (tid < 64)
        bn_sc_sh(bni_sum[tid], bni_sumsq[tid], bni_g[tid], bni_b[tid],
                 bni_invc, sSc[tid], sSh[tid]);
    __syncthreads();
    const int idx = blockIdx.x * 256 + tid;
    if (idx >= NG * NC) return;
    const int g = idx / NC, c = idx % NC;
    float acc = fo3_b[c];
    for (int k = 0; k < 64; ++k) {
        float v = fmaf(hb[g*64 + k], sSc[k], sSh[k]);
        acc = fmaf(v, fo3_w[k*NC + c], acc);
    }
    out[idx] = acc;
}

// ---------------------------------------------------------------------------
extern "C" void kernel_launch(void* const* d_in, const int* in_sizes, int n_in,
                              void* d_out, int out_size, void* d_ws, size_t ws_size,
                              hipStream_t stream) {
    const float* x         = (const float*)d_in[0];
    const int*   edge_index= (const int*)  d_in[1];
    const int*   batch     = (const int*)  d_in[2];
    const float* edge_attr = (const float*)d_in[3];
    const float* w_node    = (const float*)d_in[4];
    const float* b_node    = (const float*)d_in[5];
    const float* w_edge    = (const float*)d_in[6];
    const float* b_edge    = (const float*)d_in[7];
    const float* lin_w     = (const float*)d_in[8];
    const float* lin_b     = (const float*)d_in[9];
    const float* mlp1_w    = (const float*)d_in[10];
    const float* mlp1_b    = (const float*)d_in[11];
    const float* bn1_g     = (const float*)d_in[12];
    const float* bn1_b     = (const float*)d_in[13];
    const float* mlp2_w    = (const float*)d_in[14];
    const float* mlp2_b    = (const float*)d_in[15];
    const float* fo1_w     = (const float*)d_in[16];
    const float* fo1_b     = (const float*)d_in[17];
    const float* fo_bn1_g  = (const float*)d_in[18];
    const float* fo_bn1_b  = (const float*)d_in[19];
    const float* fo2_w     = (const float*)d_in[20];
    const float* fo2_b     = (const float*)d_in[21];
    const float* fo_bn2_g  = (const float*)d_in[22];
    const float* fo_bn2_b  = (const float*)d_in[23];
    const float* fo3_w     = (const float*)d_in[24];
    const float* fo3_b     = (const float*)d_in[25];
    float* out = (float*)d_out;

    char* ws = (char*)d_ws;
    _Float16* t16 = (_Float16*)(ws);               // 12.8 MB (CSR-build ints alias)
    int* counts = (int*)ws;                        // NN ints (dead before t16 written)
    int* next   = (int*)ws + NN;                   // NN ints (dead after scatter)
    int*   csr_src = (int*)(ws + 25600000);        // 4.8 MB
    uint4* csr_ea  = (uint4*)(ws + 30400000);      // 38.4 MB
    int* rowptr = (int*)(ws + 68800000);           // NN+1 ints
    _Float16* h16   = (_Float16*)(ws + 69300000);  // 12.8 MB
    float* sm   = (float*)(ws + 94900000);
    unsigned* Wc16 = (unsigned*)sm;  // 3*512 uints (edge weights f16)
    float* bc       = sm + 1536;     // 192
    float* bnbuf    = sm + 1728;     // 5 pairs x 128 floats (sum at +0, sumsq at +64)
    float* pooled   = sm + 2368;     // 32768
    float* ha       = sm + 35136;    // 32768
    float* hb       = sm + 67904;    // 32768
    int* bsum       = (int*)(sm + 100672);   // 512 ints
    int* bscan      = bsum + 512;            // 512 ints
    v8h* Wpk        = (v8h*)(sm + 101696);   // 7*512*16 B (16B-aligned)

    const int* src = edge_index;
    const int* dst = edge_index + NE;

    const int mfma_blocks  = (NN/16 + 3) / 4;    // 1563
    const int edge_blocks  = (NE + 255) / 256;   // 4688

    prep_kernel<<<NL, 1024, 0, stream>>>(w_edge, b_edge, lin_w, lin_b, Wc16, bc);
    pack_w_kernel<<<7, 512, 0, stream>>>(w_node, mlp1_w, mlp2_w, Wpk);

    // h16 = f16( x @ w_node + b_node )
    mfma_gemm_kernel<0, false, true, false><<<mfma_blocks, 256, 0, stream>>>(
        x, nullptr, Wpk, b_node,
        nullptr, nullptr, nullptr, nullptr, 0.f,
        h16, nullptr, nullptr);

    // CSR build (per launch; edge_index is an input)
    hipMemsetAsync(counts, 0, NN * sizeof(int), stream);
    // zero all 5 BN-stat pairs + pooled in ONE memset (contiguous region)
    hipMemsetAsync(bnbuf, 0, (640 + 32768) * sizeof(float), stream);
    hist_kernel<<<edge_blocks, 256, 0, stream>>>(dst, counts);
    scan_reduce_kernel<<<NB_SCAN, 256, 0, stream>>>(counts, bsum);
    scan_partials_kernel<<<1, 512, 0, stream>>>(bsum, bscan);
    scan_final_kernel<<<NB_SCAN, 256, 0, stream>>>(counts, bscan, rowptr, next);
    scatter_kernel<<<edge_blocks, 256, 0, stream>>>(
        src, dst, edge_attr, next, csr_src, csr_ea);

    for (int l = 0; l < NL; ++l) {
        float* bnL = bnbuf + l * 128;
        // fused: t16 = ( segsum(relu(ea@Wc + h[src])) + h ) @ mlp1_w + b, + BN stats
        agg_mlp1_kernel<<<NBLK, 128, 0, stream>>>(
            rowptr, csr_src, csr_ea, Wc16 + l*512, bc + l*64, h16,
            Wpk + (1+l)*512, mlp1_b + l*64, t16, bnL, bnL + 64);
        if (l < NL - 1) {
            // h16 = f16( relu( relu(bn(t16)) @ mlp2_w + b ) )
            mfma_gemm_kernel<2, true, true, false><<<mfma_blocks, 256, 0, stream>>>(
                nullptr, t16, Wpk + (4+l)*512, mlp2_b + l*64,
                bnL, bnL + 64, bn1_g + l*64, bn1_b + l*64, 1.0f / NN,
                h16, nullptr, nullptr);
        } else {
            // last layer: skip h16 store; pool relu(...) directly into pooled
            mfma_gemm_kernel<2, false, false, true><<<mfma_blocks, 256, 0, stream>>>(
                nullptr, t16, Wpk + (4+l)*512, mlp2_b + l*64,
                bnL, bnL + 64, bn1_g + l*64, bn1_b + l*64, 1.0f / NN,
                nullptr, batch, pooled);
        }
    }

    float* bnH1 = bnbuf + 3 * 128;
    float* bnH2 = bnbuf + 4 * 128;
    gemm64_kernel<0, false, true><<<NG/64, 256, 0, stream>>>(
        pooled, fo1_w, fo1_b,
        nullptr, nullptr, nullptr, nullptr, 0.f,
        ha, NG, bnH1, bnH1 + 64);
    gemm64_kernel<2, false, true><<<NG/64, 256, 0, stream>>>(
        ha, fo2_w, fo2_b,
        bnH1, bnH1 + 64, fo_bn1_g, fo_bn1_b, 1.0f / NG,
        hb, NG, bnH2, bnH2 + 64);
    head_final_kernel<<<(NG*NC + 255)/256, 256, 0, stream>>>(
        hb, bnH2, bnH2 + 64, fo_bn2_g, fo_bn2_b, 1.0f / NG,
        fo3_w, fo3_b, out);
}

// Round 10
// 646.278 us; speedup vs baseline: 1.2164x; 1.2164x over previous
//
#include <hip/hip_runtime.h>
#include <hip/hip_fp16.h>

#define NN 100000
#define NE 1200000
#define DD 64
#define EDIM 16
#define NL 3
#define NG 512
#define NC 10
#define NB_SCAN ((NN + 255) / 256)   // 391
#define NBLK ((NN + 63) / 64)        // 1563 fused blocks (64 nodes, 4 waves each)

typedef _Float16 f16x2 __attribute__((ext_vector_type(2)));
typedef _Float16 v8h   __attribute__((ext_vector_type(8)));
typedef float    v4f   __attribute__((ext_vector_type(4)));

__device__ __forceinline__ unsigned packh2(float a, float b) {
    f16x2 v; v[0] = (_Float16)a; v[1] = (_Float16)b;
    unsigned u; __builtin_memcpy(&u, &v, 4); return u;
}
__device__ __forceinline__ float dot2f(unsigned a, unsigned b, float c) {
    f16x2 av, bv;
    __builtin_memcpy(&av, &a, 4); __builtin_memcpy(&bv, &b, 4);
#if __has_builtin(__builtin_amdgcn_fdot2)
    return __builtin_amdgcn_fdot2(av, bv, c, false);
#else
    return c + (float)av[0]*(float)bv[0] + (float)av[1]*(float)bv[1];
#endif
}

// inline BN: scale/shift from raw sums (same math as bn_finalize incl. one
// Newton step on rsqrt -> bit-identical results, kernel fused away)
__device__ __forceinline__ void bn_sc_sh(float s, float q, float g, float b,
                                         float invc, float& sc, float& sh) {
    float mu  = s * invc;
    float var = fmaxf(q * invc - mu * mu, 0.f);
    float x = var + 1e-5f;
    float r = rsqrtf(x);
    r = r * (1.5f - 0.5f * x * r * r);
    sc = g * r;
    sh = b - mu * sc;
}

// ---------------------------------------------------------------------------
// prep: Wc[l] = w_edge @ lin_w[l] (16x64) packed to f16 pairs per column;
//       bc[l] = b_edge @ lin_w[l] + lin_b[l]  (fp32)
__global__ __launch_bounds__(1024) void prep_kernel(
    const float* __restrict__ w_edge, const float* __restrict__ b_edge,
    const float* __restrict__ lin_w, const float* __restrict__ lin_b,
    unsigned* __restrict__ Wc16, float* __restrict__ bc)
{
    __shared__ float sWc[1024];
    const int l = blockIdx.x;
    const int tid = threadIdx.x;
    const float* Lw = lin_w + l * 4096;
    const int k = tid >> 6, col = tid & 63;
    float acc = 0.f;
    for (int j = 0; j < 64; ++j) acc = fmaf(w_edge[k*64 + j], Lw[j*64 + col], acc);
    sWc[k*64 + col] = acc;
    if (tid < 64) {
        float a = lin_b[l*64 + tid];
        for (int j = 0; j < 64; ++j) a = fmaf(b_edge[j], Lw[j*64 + tid], a);
        bc[l*64 + tid] = a;
    }
    __syncthreads();
    if (tid < 512) {
        const int j = tid >> 6, c = tid & 63;     // j = pair index (dims 2j,2j+1)
        Wc16[l*512 + j*64 + c] = packh2(sWc[(2*j)*64 + c], sWc[(2*j+1)*64 + c]);
    }
}

// ---------------------------------------------------------------------------
// pack node-GEMM weights [64x64] fp32 -> f16 MFMA B-fragment order.
// m: 0 = w_node, 1..3 = mlp1_w[l], 4..6 = mlp2_w[l]
__global__ __launch_bounds__(512) void pack_w_kernel(
    const float* __restrict__ w_node, const float* __restrict__ mlp1_w,
    const float* __restrict__ mlp2_w, v8h* __restrict__ Wpk)
{
    const int m = blockIdx.x;
    const float* W = (m == 0) ? w_node
                   : (m <= 3) ? mlp1_w + (m-1)*4096
                              : mlp2_w + (m-4)*4096;
    const int fid = threadIdx.x >> 6;
    const int l   = threadIdx.x & 63;
    const int t = fid >> 1, f = fid & 1;
    const int n  = (l & 15) + 16*t;
    const int kb = f*32 + (l >> 4)*8;
    v8h v;
    #pragma unroll
    for (int j = 0; j < 8; ++j) v[j] = (_Float16)W[(kb + j)*64 + n];
    Wpk[m*512 + fid*64 + l] = v;
}

// ---------------------------------------------------------------------------
// CSR build: histogram of dst
__global__ __launch_bounds__(256) void hist_kernel(
    const int* __restrict__ dst, int* __restrict__ counts)
{
    const int e = blockIdx.x * 256 + threadIdx.x;
    if (e < NE) atomicAdd(&counts[dst[e]], 1);
}

__global__ __launch_bounds__(256) void scan_reduce_kernel(
    const int* __restrict__ counts, int* __restrict__ bsum)
{
    __shared__ int sd[256];
    const int t = threadIdx.x;
    const int idx = blockIdx.x * 256 + t;
    sd[t] = (idx < NN) ? counts[idx] : 0;
    __syncthreads();
    for (int off = 128; off > 0; off >>= 1) {
        if (t < off) sd[t] += sd[t + off];
        __syncthreads();
    }
    if (t == 0) bsum[blockIdx.x] = sd[0];
}

__global__ __launch_bounds__(512) void scan_partials_kernel(
    const int* __restrict__ bsum, int* __restrict__ bscan)
{
    __shared__ int sd[512];
    const int t = threadIdx.x;
    sd[t] = (t < NB_SCAN) ? bsum[t] : 0;
    __syncthreads();
    for (int off = 1; off < 512; off <<= 1) {
        int u = (t >= off) ? sd[t - off] : 0;
        __syncthreads();
        sd[t] += u;
        __syncthreads();
    }
    if (t < NB_SCAN) bscan[t] = (t == 0) ? 0 : sd[t - 1];
}

__global__ __launch_bounds__(256) void scan_final_kernel(
    const int* __restrict__ counts, const int* __restrict__ bscan,
    int* __restrict__ rowptr, int* __restrict__ next)
{
    __shared__ int sd[256];
    const int t = threadIdx.x;
    const int idx = blockIdx.x * 256 + t;
    const int v = (idx < NN) ? counts[idx] : 0;
    sd[t] = v;
    __syncthreads();
    for (int off = 1; off < 256; off <<= 1) {
        int u = (t >= off) ? sd[t - off] : 0;
        __syncthreads();
        sd[t] += u;
        __syncthreads();
    }
    const int excl = sd[t] - v + bscan[blockIdx.x];
    if (idx < NN) { rowptr[idx] = excl; next[idx] = excl; }
    if (idx == NN - 1) rowptr[NN] = excl + v;
}

// R2-style single-pass scatter — pinned at the per-edge random-line floor
// (R3: 8B payload still cost 80us; R4: binning loses to atomic serialization
// + cross-XCD partial lines). Pay the 1.2M random lines once, full payload.
__global__ __launch_bounds__(256) void scatter_kernel(
    const int* __restrict__ src, const int* __restrict__ dst,
    const float* __restrict__ edge_attr,
    int* __restrict__ next, int* __restrict__ csr_src, uint4* __restrict__ csr_ea)
{
    const int e = blockIdx.x * 256 + threadIdx.x;
    if (e >= NE) return;
    const float4* q = (const float4*)(edge_attr + (size_t)e * 16);
    float4 a0 = q[0], a1 = q[1], a2 = q[2], a3 = q[3];
    const int pos = atomicAdd(&next[dst[e]], 1);
    csr_src[pos] = src[e];
    uint4 A, B;
    A.x = packh2(a0.x, a0.y); A.y = packh2(a0.z, a0.w);
    A.z = packh2(a1.x, a1.y); A.w = packh2(a1.z, a1.w);
    B.x = packh2(a2.x, a2.y); B.y = packh2(a2.z, a2.w);
    B.z = packh2(a3.x, a3.y); B.w = packh2(a3.z, a3.w);
    csr_ea[(size_t)pos*2 + 0] = A;
    csr_ea[(size_t)pos*2 + 1] = B;
}

// ---------------------------------------------------------------------------
// FUSED agg + mlp1 (R10). Back to the R7 shape — 64 nodes / 4 waves — after
// R9's clean A/B: 2-wave blocks at identical per-CU wave budget ran 1.46x
// SLOWER (VALUBusy 46->31%), refuting the grid-occupancy theory. New lever:
// register-prefetched chunk staging. R7 had a serial ~1000-1500cy bubble per
// 64-edge chunk (global ea/src load -> wait -> ds_write -> ds_read before
// any h16 gather). Now chunk c+1's globals are issued right after chunk c's
// LDS writes and fly under c's ~2400cy compute; boundary cost shrinks to the
// reg->LDS write + short lgkm wait. Stale lanes past cnt are written but
// never read (all reads bounded by cnt). VGPR +9.
__global__ __launch_bounds__(256) void agg_mlp1_kernel(
    const int* __restrict__ rowptr,
    const int* __restrict__ csr_src, const uint4* __restrict__ csr_ea,
    const unsigned* __restrict__ Wc16, const float* __restrict__ bc,
    const _Float16* __restrict__ h16,
    const v8h* __restrict__ Wpk, const float* __restrict__ bias,
    _Float16* __restrict__ t16,
    float* __restrict__ bn_sum, float* __restrict__ bn_sumsq)
{
    __shared__ int rp[65];
    __shared__ __align__(16) _Float16 tile[4][16*72];  // row stride 144B
    __shared__ __align__(16) uint4 sEA[4][128];        // per-wave ea chunk; BN scratch later
    __shared__ __align__(16) int sSRC[4][64];

    const int tid  = threadIdx.x;
    const int lane = tid & 63;
    const int wv   = tid >> 6;                         // 0..3
    const int n0   = blockIdx.x * 64;

    if (tid < 65) {
        int idx = n0 + tid; if (idx > NN) idx = NN;
        rp[tid] = rowptr[idx];
    }
    // zero own tile region (576 dwords per wave)
    {
        unsigned* tz = (unsigned*)tile[wv];
        #pragma unroll
        for (int i = 0; i < 9; ++i) tz[lane + i*64] = 0u;
    }

    unsigned wq[8];
    #pragma unroll
    for (int j = 0; j < 8; ++j) wq[j] = Wc16[j*64 + lane];
    const float mb = bc[lane];

    __syncthreads();              // rp visible to all waves

    // ---------------- edge phase (per wave, nodes [n0+16w, n0+16w+16)) ----
    const int nwb  = 16 * wv;     // local first node
    const int e0   = rp[nwb];
    const int eEnd = rp[nwb + 16];
    int cur = nwb;                // local node cursor
    int nb  = rp[cur + 1];
    float acc = 0.f;

    uint4*     sEAw  = sEA[wv];
    _Float16*  tileW = tile[wv];

    auto msg = [&](uint4 A, uint4 B, float hv) -> float {
        float m = mb;
        m = dot2f(A.x, wq[0], m); m = dot2f(A.y, wq[1], m);
        m = dot2f(A.z, wq[2], m); m = dot2f(A.w, wq[3], m);
        m = dot2f(B.x, wq[4], m); m = dot2f(B.y, wq[5], m);
        m = dot2f(B.z, wq[6], m); m = dot2f(B.w, wq[7], m);
        return fmaxf(m + hv, 0.f);
    };
    auto adv = [&](int q) {       // finish current node, advance to node of edge q
        tileW[(cur - nwb)*72 + lane] = (_Float16)acc;
        acc = 0.f;
        do { ++cur; } while (rp[cur + 1] <= q);
        nb = rp[cur + 1];
    };
    auto doGroup = [&](const uint4* eg, int p,
                       float hv0, float hv1, float hv2, float hv3) {
        float m0, m1, m2, m3;
        { uint4 A = eg[0], B = eg[1]; m0 = msg(A, B, hv0); }
        { uint4 A = eg[2], B = eg[3]; m1 = msg(A, B, hv1); }
        { uint4 A = eg[4], B = eg[5]; m2 = msg(A, B, hv2); }
        { uint4 A = eg[6], B = eg[7]; m3 = msg(A, B, hv3); }
        if (p + 3 < nb) {                            // wave-uniform fast path
            acc += (m0 + m1) + (m2 + m3);
        } else {
            if (p     >= nb) adv(p);     acc += m0;
            if (p + 1 >= nb) adv(p + 1); acc += m1;
            if (p + 2 >= nb) adv(p + 2); acc += m2;
            if (p + 3 >= nb) adv(p + 3); acc += m3;
        }
    };

    // register prefetch of the first chunk
    uint4 rA = uint4{0,0,0,0}, rB = uint4{0,0,0,0};
    int   rS = 0;
    if (e0 < eEnd) {
        const int cnt0 = min(64, eEnd - e0);
        if (lane < 2*cnt0)      rA = csr_ea[(size_t)e0*2 + lane];
        if (64 + lane < 2*cnt0) rB = csr_ea[(size_t)e0*2 + 64 + lane];
        if (lane < cnt0)        rS = csr_src[e0 + lane];
    }

    for (int base = e0; base < eEnd; base += 64) {
        const int cnt = min(64, eEnd - base);
        // write staged regs to LDS (wave-local, no barrier needed)
        sEAw[lane]      = rA;
        sEAw[64 + lane] = rB;
        sSRC[wv][lane]  = rS;
        // issue NEXT chunk's global loads now — latency hides under compute
        const int nbase = base + 64;
        if (nbase < eEnd) {
            const int ncnt = min(64, eEnd - nbase);
            if (lane < 2*ncnt)      rA = csr_ea[(size_t)nbase*2 + lane];
            if (64 + lane < 2*ncnt) rB = csr_ea[(size_t)nbase*2 + 64 + lane];
            if (lane < ncnt)        rS = csr_src[nbase + lane];
        }

        const int grpN = cnt >> 2;
        if (grpN) {
            int4 s = *(const int4*)&sSRC[wv][0];
            _Float16 hA0 = h16[(size_t)s.x*64 + lane];
            _Float16 hA1 = h16[(size_t)s.y*64 + lane];
            _Float16 hA2 = h16[(size_t)s.z*64 + lane];
            _Float16 hA3 = h16[(size_t)s.w*64 + lane];
            #pragma unroll 1
            for (int gp = 0; gp < grpN; ++gp) {
                // issue next group's gathers (clamped; redundant on last iter)
                const int gn = (gp + 1 < grpN) ? gp + 1 : gp;
                int4 sn = *(const int4*)&sSRC[wv][gn*4];
                _Float16 hB0 = h16[(size_t)sn.x*64 + lane];
                _Float16 hB1 = h16[(size_t)sn.y*64 + lane];
                _Float16 hB2 = h16[(size_t)sn.z*64 + lane];
                _Float16 hB3 = h16[(size_t)sn.w*64 + lane];
                doGroup(sEAw + gp*8, base + gp*4,
                        (float)hA0, (float)hA1, (float)hA2, (float)hA3);
                hA0 = hB0; hA1 = hB1; hA2 = hB2; hA3 = hB3;
            }
        }
        for (int k = grpN*4; k < cnt; ++k) {         // chunk tail (0-3 edges)
            const int p = base + k;
            const int sv = sSRC[wv][k];
            const float hv = (float)h16[(size_t)sv*64 + lane];
            uint4 A = sEAw[k*2], B = sEAw[k*2 + 1];
            const float m = msg(A, B, hv);
            if (p >= nb) adv(p);
            acc += m;
        }
    }
    if (e0 < eEnd)                                   // final node flush
        tileW[(cur - nwb)*72 + lane] = (_Float16)acc;

    // ---------------- MFMA phase (mlp1) — no barrier: own rows only -------
    const int li = lane & 15, quad = lane >> 4;
    const int rb = n0 + nwb;
    const bool active = (rb < NN);                   // NN % 16 == 0

    v8h Bf[8];
    #pragma unroll
    for (int i = 0; i < 8; ++i) Bf[i] = Wpk[i*64 + lane];

    v4f accm[4] = {v4f{0,0,0,0}, v4f{0,0,0,0}, v4f{0,0,0,0}, v4f{0,0,0,0}};
    if (active) {
        const _Float16* trow = tileW + li*72 + quad*8;
        v8h Af0 = *(const v8h*)(trow);
        v8h Af1 = *(const v8h*)(trow + 32);
        const size_t off = (size_t)(rb + li)*64 + quad*8;
        Af0 += *(const v8h*)(h16 + off);             // self term "+h"
        Af1 += *(const v8h*)(h16 + off + 32);
        #pragma unroll
        for (int t = 0; t < 4; ++t) {
            accm[t] = __builtin_amdgcn_mfma_f32_16x16x32_f16(Af0, Bf[t*2+0], accm[t], 0, 0, 0);
            accm[t] = __builtin_amdgcn_mfma_f32_16x16x32_f16(Af1, Bf[t*2+1], accm[t], 0, 0, 0);
        }
    }

    float ps[4] = {0.f, 0.f, 0.f, 0.f}, pq[4] = {0.f, 0.f, 0.f, 0.f};
    if (active) {
        #pragma unroll
        for (int t = 0; t < 4; ++t) {
            const int col = li + 16*t;
            const float bcol = bias[col];
            #pragma unroll
            for (int r = 0; r < 4; ++r) {
                const int row = rb + quad*4 + r;
                float v = accm[t][r] + bcol;
                ps[t] += v; pq[t] += v*v;            // BN stats on fp32 value
                t16[(size_t)row*64 + col] = (_Float16)v;
            }
        }
    }

    // BN partial reduction: sEA[wv] reused as per-wave sS(256f)+sQ(256f)
    float* sSw = (float*)sEA[wv];
    #pragma unroll
    for (int t = 0; t < 4; ++t) {
        sSw[lane*4 + t]       = ps[t];
        sSw[256 + lane*4 + t] = pq[t];
    }
    __syncthreads();
    if (tid < 64) {
        const int t = tid >> 4, li2 = tid & 15;
        float s = 0.f, q = 0.f;
        #pragma unroll
        for (int w = 0; w < 4; ++w) {
            const float* pS = (const float*)sEA[w];
            #pragma unroll
            for (int qd = 0; qd < 4; ++qd) {
                const int idx = (qd*16 + li2)*4 + t;
                s += pS[idx]; q += pS[256 + idx];
            }
        }
        atomicAdd(bn_sum + tid, s);
        atomicAdd(bn_sumsq + tid, q);
    }
}

// ---------------------------------------------------------------------------
// MFMA node GEMM: [NN,64] @ [64,64] + bias.
// IN_MODE 0: A = fp32 raw (in0). IN_MODE 2: A = relu(bn(f16 in16)) with
// scale/shift computed inline from raw BN sums.
// OUT_HALF stores f16; OUT_POOL atomically accumulates relu(v) into
// pooled[batch[row]] (wave-level shfl reduction on the sorted-batch fast path).
template<int IN_MODE, bool OUT_RELU, bool OUT_HALF, bool OUT_POOL>
__global__ __launch_bounds__(256) void mfma_gemm_kernel(
    const float* __restrict__ in0, const _Float16* __restrict__ in16,
    const v8h* __restrict__ Wpk, const float* __restrict__ bias,
    const float* __restrict__ bni_sum, const float* __restrict__ bni_sumsq,
    const float* __restrict__ bni_g, const float* __restrict__ bni_b,
    float bni_invc,
    _Float16* __restrict__ out16,
    const int* __restrict__ batch, float* __restrict__ pooled)
{
    __shared__ float sSc[64], sSh[64];
    const int tid = threadIdx.x;
    const int wv = tid >> 6, l = tid & 63;
    const int li = l & 15, quad = l >> 4;
    const int rb = (blockIdx.x * 4 + wv) * 16;   // row-block base
    const bool active = (rb < NN);               // NN % 16 == 0

    if constexpr (IN_MODE == 2) {
        if (tid < 64)
            bn_sc_sh(bni_sum[tid], bni_sumsq[tid], bni_g[tid], bni_b[tid],
                     bni_invc, sSc[tid], sSh[tid]);
        __syncthreads();
    }

    v8h Bf[8];
    #pragma unroll
    for (int i = 0; i < 8; ++i) Bf[i] = Wpk[i*64 + l];

    v4f acc[4] = {v4f{0,0,0,0}, v4f{0,0,0,0}, v4f{0,0,0,0}, v4f{0,0,0,0}};

    if (active) {
        v8h Af[2];
        if constexpr (IN_MODE == 2) {
            const _Float16* arow = in16 + (size_t)(rb + li)*64 + quad*8;
            v8h r0 = *(const v8h*)(arow);
            v8h r1 = *(const v8h*)(arow + 32);
            v8h a0, a1;
            #pragma unroll
            for (int j = 0; j < 8; ++j) {
                const int k0 = quad*8 + j;
                const int k1 = 32 + quad*8 + j;
                a0[j] = (_Float16)fmaxf(fmaf((float)r0[j], sSc[k0], sSh[k0]), 0.f);
                a1[j] = (_Float16)fmaxf(fmaf((float)r1[j], sSc[k1], sSh[k1]), 0.f);
            }
            Af[0] = a0; Af[1] = a1;
        } else {
            const float* arow = in0 + (size_t)(rb + li)*64 + quad*8;
            #pragma unroll
            for (int f = 0; f < 2; ++f) {
                float4 x0 = *(const float4*)(arow + f*32);
                float4 x1 = *(const float4*)(arow + f*32 + 4);
                v8h a;
                a[0] = (_Float16)x0.x; a[1] = (_Float16)x0.y;
                a[2] = (_Float16)x0.z; a[3] = (_Float16)x0.w;
                a[4] = (_Float16)x1.x; a[5] = (_Float16)x1.y;
                a[6] = (_Float16)x1.z; a[7] = (_Float16)x1.w;
                Af[f] = a;
            }
        }
        #pragma unroll
        for (int t = 0; t < 4; ++t) {
            acc[t] = __builtin_amdgcn_mfma_f32_16x16x32_f16(Af[0], Bf[t*2+0], acc[t], 0, 0, 0);
            acc[t] = __builtin_amdgcn_mfma_f32_16x16x32_f16(Af[1], Bf[t*2+1], acc[t], 0, 0, 0);
        }
    }

    if constexpr (OUT_HALF) {
        if (active) {
            #pragma unroll
            for (int t = 0; t < 4; ++t) {
                const int col = li + 16*t;
                const float bcol = bias[col];
                #pragma unroll
                for (int r = 0; r < 4; ++r) {
                    const int row = rb + quad*4 + r;
                    float v = acc[t][r] + bcol;
                    if constexpr (OUT_RELU) v = fmaxf(v, 0.f);
                    out16[(size_t)row*64 + col] = (_Float16)v;
                }
            }
        }
    }

    if constexpr (OUT_POOL) {
        if (active) {
            const int b0  = batch[rb];
            const int b15 = batch[rb + 15];
            if (b0 == b15) {            // whole wave's 16 rows in one graph
                #pragma unroll
                for (int t = 0; t < 4; ++t) {
                    const int col = li + 16*t;
                    const float bcol = bias[col];
                    float s = 0.f;
                    #pragma unroll
                    for (int r = 0; r < 4; ++r)
                        s += fmaxf(acc[t][r] + bcol, 0.f);
                    s += __shfl_xor(s, 16);
                    s += __shfl_xor(s, 32);
                    if (quad == 0) atomicAdd(&pooled[b0*64 + col], s);
                }
            } else {                    // rare straddling wave: per-row
                #pragma unroll
                for (int t = 0; t < 4; ++t) {
                    const int col = li + 16*t;
                    const float bcol = bias[col];
                    #pragma unroll
                    for (int r = 0; r < 4; ++r) {
                        const int row = rb + quad*4 + r;
                        const float v = fmaxf(acc[t][r] + bcol, 0.f);
                        atomicAdd(&pooled[batch[row]*64 + col], v);
                    }
                }
            }
        }
    }
}

// ---------------------------------------------------------------------------
// small vector GEMM for the 512-row head.
// IN_MODE==2 applies relu(bn(x)) during load; scale/shift inline from raw sums.
template<int IN_MODE, bool OUT_RELU, bool OUT_ACCUM>
__global__ __launch_bounds__(256) void gemm64_kernel(
    const float* __restrict__ in0,
    const float* __restrict__ W, const float* __restrict__ bias,
    const float* __restrict__ bni_sum, const float* __restrict__ bni_sumsq,
    const float* __restrict__ bni_g, const float* __restrict__ bni_b,
    float bni_invc,
    float* __restrict__ out, int nrows,
    float* __restrict__ bn_sum, float* __restrict__ bn_sumsq)
{
    __shared__ __align__(16) float sIn[64*64];
    __shared__ float sRedS[512];
    __shared__ float sRedQ[512];
    __shared__ __align__(16) float sSc[64], sSh[64];
    const int tid = threadIdx.x;
    const int c  = tid & 31;
    const int rg = tid >> 5;
    const int r0 = blockIdx.x * 64;

    if constexpr (IN_MODE == 2) {
        if (tid < 64)
            bn_sc_sh(bni_sum[tid], bni_sumsq[tid], bni_g[tid], bni_b[tid],
                     bni_invc, sSc[tid], sSh[tid]);
        __syncthreads();
    }

    float w0[64], w1[64];
    #pragma unroll
    for (int k = 0; k < 64; ++k) { w0[k] = W[k*64 + c]; w1[k] = W[k*64 + c + 32]; }
    const float b0 = bias[c], b1 = bias[c + 32];

    for (int i = tid; i < 1024; i += 256) {
        const int r  = i >> 4;
        const int c4 = (i & 15) * 4;
        const int gr = r0 + r;
        float4 v = make_float4(0.f, 0.f, 0.f, 0.f);
        if (gr < nrows) {
            v = *(const float4*)(in0 + (size_t)gr*64 + c4);
            if constexpr (IN_MODE == 2) {
                float4 s4 = *(const float4*)(sSc + c4);
                float4 h4 = *(const float4*)(sSh + c4);
                v.x = fmaxf(fmaf(v.x, s4.x, h4.x), 0.f);
                v.y = fmaxf(fmaf(v.y, s4.y, h4.y), 0.f);
                v.z = fmaxf(fmaf(v.z, s4.z, h4.z), 0.f);
                v.w = fmaxf(fmaf(v.w, s4.w, h4.w), 0.f);
            }
        }
        *(float4*)(sIn + r*64 + c4) = v;
    }
    __syncthreads();

    float ps0 = 0.f, psq0 = 0.f, ps1 = 0.f, psq1 = 0.f;
    #pragma unroll
    for (int i = 0; i < 8; ++i) {
        const int r = rg + 8*i;
        float a0 = b0, a1 = b1;
        #pragma unroll
        for (int k = 0; k < 64; k += 4) {
            float4 a = *(const float4*)(sIn + r*64 + k);
            a0 = fmaf(a.x, w0[k+0], a0); a1 = fmaf(a.x, w1[k+0], a1);
            a0 = fmaf(a.y, w0[k+1], a0); a1 = fmaf(a.y, w1[k+1], a1);
            a0 = fmaf(a.z, w0[k+2], a0); a1 = fmaf(a.z, w1[k+2], a1);
            a0 = fmaf(a.w, w0[k+3], a0); a1 = fmaf(a.w, w1[k+3], a1);
        }
        const int gr = r0 + r;
        if (gr < nrows) {
            if constexpr (OUT_ACCUM) {
                ps0 += a0; psq0 += a0*a0;
                ps1 += a1; psq1 += a1*a1;
            }
            out[(size_t)gr*64 + c]      = OUT_RELU ? fmaxf(a0, 0.f) : a0;
            out[(size_t)gr*64 + c + 32] = OUT_RELU ? fmaxf(a1, 0.f) : a1;
        }
    }

    if constexpr (OUT_ACCUM) {
        sRedS[rg*64 + c]      = ps0;
        sRedS[rg*64 + c + 32] = ps1;
        sRedQ[rg*64 + c]      = psq0;
        sRedQ[rg*64 + c + 32] = psq1;
        __syncthreads();
        if (tid < 64) {
            float s = 0.f, q = 0.f;
            #pragma unroll
            for (int g = 0; g < 8; ++g) { s += sRedS[g*64 + tid]; q += sRedQ[g*64 + tid]; }
            atomicAdd(bn_sum + tid, s);
            atomicAdd(bn_sumsq + tid, q);
        }
    }
}

// ---------------------------------------------------------------------------
// final head: out = bn(hb) @ fo3_w + fo3_b, BN inline from raw sums
__global__ __launch_bounds__(256) void head_final_kernel(
    const float* __restrict__ hb,
    const float* __restrict__ bni_sum, const float* __restrict__ bni_sumsq,
    const float* __restrict__ bni_g, const float* __restrict__ bni_b,
    float bni_invc,
    const float* __restrict__ fo3_w, const float* __restrict__ fo3_b,
    float* __restrict__ out)
{
    __shared__ float sSc[64], sSh[64];
    const int tid = threadIdx.x;
    if (tid < 64)
        bn_sc_sh(bni_sum[tid], bni_sumsq[tid], bni_g[tid], bni_b[tid],
                 bni_invc, sSc[tid], sSh[tid]);
    __syncthreads();
    const int idx = blockIdx.x * 256 + tid;
    if (idx >= NG * NC) return;
    const int g = idx / NC, c = idx % NC;
    float acc = fo3_b[c];
    for (int k = 0; k < 64; ++k) {
        float v = fmaf(hb[g*64 + k], sSc[k], sSh[k]);
        acc = fmaf(v, fo3_w[k*NC + c], acc);
    }
    out[idx] = acc;
}

// ---------------------------------------------------------------------------
extern "C" void kernel_launch(void* const* d_in, const int* in_sizes, int n_in,
                              void* d_out, int out_size, void* d_ws, size_t ws_size,
                              hipStream_t stream) {
    const float* x         = (const float*)d_in[0];
    const int*   edge_index= (const int*)  d_in[1];
    const int*   batch     = (const int*)  d_in[2];
    const float* edge_attr = (const float*)d_in[3];
    const float* w_node    = (const float*)d_in[4];
    const float* b_node    = (const float*)d_in[5];
    const float* w_edge    = (const float*)d_in[6];
    const float* b_edge    = (const float*)d_in[7];
    const float* lin_w     = (const float*)d_in[8];
    const float* lin_b     = (const float*)d_in[9];
    const float* mlp1_w    = (const float*)d_in[10];
    const float* mlp1_b    = (const float*)d_in[11];
    const float* bn1_g     = (const float*)d_in[12];
    const float* bn1_b     = (const float*)d_in[13];
    const float* mlp2_w    = (const float*)d_in[14];
    const float* mlp2_b    = (const float*)d_in[15];
    const float* fo1_w     = (const float*)d_in[16];
    const float* fo1_b     = (const float*)d_in[17];
    const float* fo_bn1_g  = (const float*)d_in[18];
    const float* fo_bn1_b  = (const float*)d_in[19];
    const float* fo2_w     = (const float*)d_in[20];
    const float* fo2_b     = (const float*)d_in[21];
    const float* fo_bn2_g  = (const float*)d_in[22];
    const float* fo_bn2_b  = (const float*)d_in[23];
    const float* fo3_w     = (const float*)d_in[24];
    const float* fo3_b     = (const float*)d_in[25];
    float* out = (float*)d_out;

    char* ws = (char*)d_ws;
    _Float16* t16 = (_Float16*)(ws);               // 12.8 MB (CSR-build ints alias)
    int* counts = (int*)ws;                        // NN ints (dead before t16 written)
    int* next   = (int*)ws + NN;                   // NN ints (dead after scatter)
    int*   csr_src = (int*)(ws + 25600000);        // 4.8 MB
    uint4* csr_ea  = (uint4*)(ws + 30400000);      // 38.4 MB
    int* rowptr = (int*)(ws + 68800000);           // NN+1 ints
    _Float16* h16   = (_Float16*)(ws + 69300000);  // 12.8 MB
    float* sm   = (float*)(ws + 94900000);
    unsigned* Wc16 = (unsigned*)sm;  // 3*512 uints (edge weights f16)
    float* bc       = sm + 1536;     // 192
    float* bnbuf    = sm + 1728;     // 5 pairs x 128 floats (sum at +0, sumsq at +64)
    float* pooled   = sm + 2368;     // 32768
    float* ha       = sm + 35136;    // 32768
    float* hb       = sm + 67904;    // 32768
    int* bsum       = (int*)(sm + 100672);   // 512 ints
    int* bscan      = bsum + 512;            // 512 ints
    v8h* Wpk        = (v8h*)(sm + 101696);   // 7*512*16 B (16B-aligned)

    const int* src = edge_index;
    const int* dst = edge_index + NE;

    const int mfma_blocks  = (NN/16 + 3) / 4;    // 1563
    const int edge_blocks  = (NE + 255) / 256;   // 4688

    prep_kernel<<<NL, 1024, 0, stream>>>(w_edge, b_edge, lin_w, lin_b, Wc16, bc);
    pack_w_kernel<<<7, 512, 0, stream>>>(w_node, mlp1_w, mlp2_w, Wpk);

    // h16 = f16( x @ w_node + b_node )
    mfma_gemm_kernel<0, false, true, false><<<mfma_blocks, 256, 0, stream>>>(
        x, nullptr, Wpk, b_node,
        nullptr, nullptr, nullptr, nullptr, 0.f,
        h16, nullptr, nullptr);

    // CSR build (per launch; edge_index is an input)
    hipMemsetAsync(counts, 0, NN * sizeof(int), stream);
    // zero all 5 BN-stat pairs + pooled in ONE memset (contiguous region)
    hipMemsetAsync(bnbuf, 0, (640 + 32768) * sizeof(float), stream);
    hist_kernel<<<edge_blocks, 256, 0, stream>>>(dst, counts);
    scan_reduce_kernel<<<NB_SCAN, 256, 0, stream>>>(counts, bsum);
    scan_partials_kernel<<<1, 512, 0, stream>>>(bsum, bscan);
    scan_final_kernel<<<NB_SCAN, 256, 0, stream>>>(counts, bscan, rowptr, next);
    scatter_kernel<<<edge_blocks, 256, 0, stream>>>(
        src, dst, edge_attr, next, csr_src, csr_ea);

    for (int l = 0; l < NL; ++l) {
        float* bnL = bnbuf + l * 128;
        // fused: t16 = ( segsum(relu(ea@Wc + h[src])) + h ) @ mlp1_w + b, + BN stats
        agg_mlp1_kernel<<<NBLK, 256, 0, stream>>>(
            rowptr, csr_src, csr_ea, Wc16 + l*512, bc + l*64, h16,
            Wpk + (1+l)*512, mlp1_b + l*64, t16, bnL, bnL + 64);
        if (l < NL - 1) {
            // h16 = f16( relu( relu(bn(t16)) @ mlp2_w + b ) )
            mfma_gemm_kernel<2, true, true, false><<<mfma_blocks, 256, 0, stream>>>(
                nullptr, t16, Wpk + (4+l)*512, mlp2_b + l*64,
                bnL, bnL + 64, bn1_g + l*64, bn1_b + l*64, 1.0f / NN,
                h16, nullptr, nullptr);
        } else {
            // last layer: skip h16 store; pool relu(...) directly into pooled
            mfma_gemm_kernel<2, false, false, true><<<mfma_blocks, 256, 0, stream>>>(
                nullptr, t16, Wpk + (4+l)*512, mlp2_b + l*64,
                bnL, bnL + 64, bn1_g + l*64, bn1_b + l*64, 1.0f / NN,
                nullptr, batch, pooled);
        }
    }

    float* bnH1 = bnbuf + 3 * 128;
    float* bnH2 = bnbuf + 4 * 128;
    gemm64_kernel<0, false, true><<<NG/64, 256, 0, stream>>>(
        pooled, fo1_w, fo1_b,
        nullptr, nullptr, nullptr, nullptr, 0.f,
        ha, NG, bnH1, bnH1 + 64);
    gemm64_kernel<2, false, true><<<NG/64, 256, 0, stream>>>(
        ha, fo2_w, fo2_b,
        bnH1, bnH1 + 64, fo_bn1_g, fo_bn1_b, 1.0f / NG,
        hb, NG, bnH2, bnH2 + 64);
    head_final_kernel<<<(NG*NC + 255)/256, 256, 0, stream>>>(
        hb, bnH2, bnH2 + 64, fo_bn2_g, fo_bn2_b, 1.0f / NG,
        fo3_w, fo3_b, out);
}

// Round 11
// 642.990 us; speedup vs baseline: 1.2226x; 1.0051x over previous
//
#include <hip/hip_runtime.h>
#include <hip/hip_fp16.h>

#define NN 100000
#define NE 1200000
#define DD 64
#define EDIM 16
#define NL 3
#define NG 512
#define NC 10
#define NB_SCAN ((NN + 255) / 256)   // 391
#define NBLK ((NN + 63) / 64)        // 1563 fused blocks (64 nodes, 4 waves each)

typedef _Float16 f16x2 __attribute__((ext_vector_type(2)));
typedef _Float16 v8h   __attribute__((ext_vector_type(8)));
typedef float    v4f   __attribute__((ext_vector_type(4)));

__device__ __forceinline__ unsigned packh2(float a, float b) {
    f16x2 v; v[0] = (_Float16)a; v[1] = (_Float16)b;
    unsigned u; __builtin_memcpy(&u, &v, 4); return u;
}
__device__ __forceinline__ float dot2f(unsigned a, unsigned b, float c) {
    f16x2 av, bv;
    __builtin_memcpy(&av, &a, 4); __builtin_memcpy(&bv, &b, 4);
#if __has_builtin(__builtin_amdgcn_fdot2)
    return __builtin_amdgcn_fdot2(av, bv, c, false);
#else
    return c + (float)av[0]*(float)bv[0] + (float)av[1]*(float)bv[1];
#endif
}

// inline BN: scale/shift from raw sums (same math as bn_finalize incl. one
// Newton step on rsqrt -> bit-identical results, kernel fused away)
__device__ __forceinline__ void bn_sc_sh(float s, float q, float g, float b,
                                         float invc, float& sc, float& sh) {
    float mu  = s * invc;
    float var = fmaxf(q * invc - mu * mu, 0.f);
    float x = var + 1e-5f;
    float r = rsqrtf(x);
    r = r * (1.5f - 0.5f * x * r * r);
    sc = g * r;
    sh = b - mu * sc;
}

// ---------------------------------------------------------------------------
// prep: Wc[l] = w_edge @ lin_w[l] (16x64) packed to f16 pairs per column;
//       bc[l] = b_edge @ lin_w[l] + lin_b[l]  (fp32)
__global__ __launch_bounds__(1024) void prep_kernel(
    const float* __restrict__ w_edge, const float* __restrict__ b_edge,
    const float* __restrict__ lin_w, const float* __restrict__ lin_b,
    unsigned* __restrict__ Wc16, float* __restrict__ bc)
{
    __shared__ float sWc[1024];
    const int l = blockIdx.x;
    const int tid = threadIdx.x;
    const float* Lw = lin_w + l * 4096;
    const int k = tid >> 6, col = tid & 63;
    float acc = 0.f;
    for (int j = 0; j < 64; ++j) acc = fmaf(w_edge[k*64 + j], Lw[j*64 + col], acc);
    sWc[k*64 + col] = acc;
    if (tid < 64) {
        float a = lin_b[l*64 + tid];
        for (int j = 0; j < 64; ++j) a = fmaf(b_edge[j], Lw[j*64 + tid], a);
        bc[l*64 + tid] = a;
    }
    __syncthreads();
    if (tid < 512) {
        const int j = tid >> 6, c = tid & 63;     // j = pair index (dims 2j,2j+1)
        Wc16[l*512 + j*64 + c] = packh2(sWc[(2*j)*64 + c], sWc[(2*j+1)*64 + c]);
    }
}

// ---------------------------------------------------------------------------
// pack node-GEMM weights [64x64] fp32 -> f16 MFMA B-fragment order.
// m: 0 = w_node, 1..3 = mlp1_w[l], 4..6 = mlp2_w[l]
__global__ __launch_bounds__(512) void pack_w_kernel(
    const float* __restrict__ w_node, const float* __restrict__ mlp1_w,
    const float* __restrict__ mlp2_w, v8h* __restrict__ Wpk)
{
    const int m = blockIdx.x;
    const float* W = (m == 0) ? w_node
                   : (m <= 3) ? mlp1_w + (m-1)*4096
                              : mlp2_w + (m-4)*4096;
    const int fid = threadIdx.x >> 6;
    const int l   = threadIdx.x & 63;
    const int t = fid >> 1, f = fid & 1;
    const int n  = (l & 15) + 16*t;
    const int kb = f*32 + (l >> 4)*8;
    v8h v;
    #pragma unroll
    for (int j = 0; j < 8; ++j) v[j] = (_Float16)W[(kb + j)*64 + n];
    Wpk[m*512 + fid*64 + l] = v;
}

// ---------------------------------------------------------------------------
// CSR build: histogram of dst
__global__ __launch_bounds__(256) void hist_kernel(
    const int* __restrict__ dst, int* __restrict__ counts)
{
    const int e = blockIdx.x * 256 + threadIdx.x;
    if (e < NE) atomicAdd(&counts[dst[e]], 1);
}

__global__ __launch_bounds__(256) void scan_reduce_kernel(
    const int* __restrict__ counts, int* __restrict__ bsum)
{
    __shared__ int sd[256];
    const int t = threadIdx.x;
    const int idx = blockIdx.x * 256 + t;
    sd[t] = (idx < NN) ? counts[idx] : 0;
    __syncthreads();
    for (int off = 128; off > 0; off >>= 1) {
        if (t < off) sd[t] += sd[t + off];
        __syncthreads();
    }
    if (t == 0) bsum[blockIdx.x] = sd[0];
}

__global__ __launch_bounds__(512) void scan_partials_kernel(
    const int* __restrict__ bsum, int* __restrict__ bscan)
{
    __shared__ int sd[512];
    const int t = threadIdx.x;
    sd[t] = (t < NB_SCAN) ? bsum[t] : 0;
    __syncthreads();
    for (int off = 1; off < 512; off <<= 1) {
        int u = (t >= off) ? sd[t - off] : 0;
        __syncthreads();
        sd[t] += u;
        __syncthreads();
    }
    if (t < NB_SCAN) bscan[t] = (t == 0) ? 0 : sd[t - 1];
}

__global__ __launch_bounds__(256) void scan_final_kernel(
    const int* __restrict__ counts, const int* __restrict__ bscan,
    int* __restrict__ rowptr, int* __restrict__ next)
{
    __shared__ int sd[256];
    const int t = threadIdx.x;
    const int idx = blockIdx.x * 256 + t;
    const int v = (idx < NN) ? counts[idx] : 0;
    sd[t] = v;
    __syncthreads();
    for (int off = 1; off < 256; off <<= 1) {
        int u = (t >= off) ? sd[t - off] : 0;
        __syncthreads();
        sd[t] += u;
        __syncthreads();
    }
    const int excl = sd[t] - v + bscan[blockIdx.x];
    if (idx < NN) { rowptr[idx] = excl; next[idx] = excl; }
    if (idx == NN - 1) rowptr[NN] = excl + v;
}

// R2-style single-pass scatter — pinned at the per-edge random-line floor
// (R3: 8B payload still cost 80us; R4: binning loses to atomic serialization
// + cross-XCD partial lines). Pay the 1.2M random lines once, full payload.
__global__ __launch_bounds__(256) void scatter_kernel(
    const int* __restrict__ src, const int* __restrict__ dst,
    const float* __restrict__ edge_attr,
    int* __restrict__ next, int* __restrict__ csr_src, uint4* __restrict__ csr_ea)
{
    const int e = blockIdx.x * 256 + threadIdx.x;
    if (e >= NE) return;
    const float4* q = (const float4*)(edge_attr + (size_t)e * 16);
    float4 a0 = q[0], a1 = q[1], a2 = q[2], a3 = q[3];
    const int pos = atomicAdd(&next[dst[e]], 1);
    csr_src[pos] = src[e];
    uint4 A, B;
    A.x = packh2(a0.x, a0.y); A.y = packh2(a0.z, a0.w);
    A.z = packh2(a1.x, a1.y); A.w = packh2(a1.z, a1.w);
    B.x = packh2(a2.x, a2.y); B.y = packh2(a2.z, a2.w);
    B.z = packh2(a3.x, a3.y); B.w = packh2(a3.z, a3.w);
    csr_ea[(size_t)pos*2 + 0] = A;
    csr_ea[(size_t)pos*2 + 1] = B;
}

// ---------------------------------------------------------------------------
// FUSED agg + mlp1 (R11: 4-deep h16 gather pipeline). R10's chunk-staging
// prefetch was null -> the stall is the per-wave dependent-gather chain:
// depth-1 prefetch + ~3 resident waves covers only ~300-400cy of the
// ~600-900cy gather latency (VALUBusy stuck at 47%). Now gathers are issued
// 3 groups (12 edges) ahead via 4 statically-named register buffers with
// explicit rotation (rule #20: all indices compile-time) -> ~4x104cy own
// compute + co-resident waves > 900cy = full coverage. Clamped re-issue at
// chunk tails is redundant-but-hot. Rest unchanged from R10.
__global__ __launch_bounds__(256) void agg_mlp1_kernel(
    const int* __restrict__ rowptr,
    const int* __restrict__ csr_src, const uint4* __restrict__ csr_ea,
    const unsigned* __restrict__ Wc16, const float* __restrict__ bc,
    const _Float16* __restrict__ h16,
    const v8h* __restrict__ Wpk, const float* __restrict__ bias,
    _Float16* __restrict__ t16,
    float* __restrict__ bn_sum, float* __restrict__ bn_sumsq)
{
    __shared__ int rp[65];
    __shared__ __align__(16) _Float16 tile[4][16*72];  // row stride 144B
    __shared__ __align__(16) uint4 sEA[4][128];        // per-wave ea chunk; BN scratch later
    __shared__ __align__(16) int sSRC[4][64];

    const int tid  = threadIdx.x;
    const int lane = tid & 63;
    const int wv   = tid >> 6;                         // 0..3
    const int n0   = blockIdx.x * 64;

    if (tid < 65) {
        int idx = n0 + tid; if (idx > NN) idx = NN;
        rp[tid] = rowptr[idx];
    }
    // zero own tile region (576 dwords per wave)
    {
        unsigned* tz = (unsigned*)tile[wv];
        #pragma unroll
        for (int i = 0; i < 9; ++i) tz[lane + i*64] = 0u;
    }

    unsigned wq[8];
    #pragma unroll
    for (int j = 0; j < 8; ++j) wq[j] = Wc16[j*64 + lane];
    const float mb = bc[lane];

    __syncthreads();              // rp visible to all waves

    // ---------------- edge phase (per wave, nodes [n0+16w, n0+16w+16)) ----
    const int nwb  = 16 * wv;     // local first node
    const int e0   = rp[nwb];
    const int eEnd = rp[nwb + 16];
    int cur = nwb;                // local node cursor
    int nb  = rp[cur + 1];
    float acc = 0.f;

    uint4*     sEAw  = sEA[wv];
    _Float16*  tileW = tile[wv];

    auto msg = [&](uint4 A, uint4 B, float hv) -> float {
        float m = mb;
        m = dot2f(A.x, wq[0], m); m = dot2f(A.y, wq[1], m);
        m = dot2f(A.z, wq[2], m); m = dot2f(A.w, wq[3], m);
        m = dot2f(B.x, wq[4], m); m = dot2f(B.y, wq[5], m);
        m = dot2f(B.z, wq[6], m); m = dot2f(B.w, wq[7], m);
        return fmaxf(m + hv, 0.f);
    };
    auto adv = [&](int q) {       // finish current node, advance to node of edge q
        tileW[(cur - nwb)*72 + lane] = (_Float16)acc;
        acc = 0.f;
        do { ++cur; } while (rp[cur + 1] <= q);
        nb = rp[cur + 1];
    };
    auto doGroup = [&](const uint4* eg, int p,
                       float hv0, float hv1, float hv2, float hv3) {
        float m0, m1, m2, m3;
        { uint4 A = eg[0], B = eg[1]; m0 = msg(A, B, hv0); }
        { uint4 A = eg[2], B = eg[3]; m1 = msg(A, B, hv1); }
        { uint4 A = eg[4], B = eg[5]; m2 = msg(A, B, hv2); }
        { uint4 A = eg[6], B = eg[7]; m3 = msg(A, B, hv3); }
        if (p + 3 < nb) {                            // wave-uniform fast path
            acc += (m0 + m1) + (m2 + m3);
        } else {
            if (p     >= nb) adv(p);     acc += m0;
            if (p + 1 >= nb) adv(p + 1); acc += m1;
            if (p + 2 >= nb) adv(p + 2); acc += m2;
            if (p + 3 >= nb) adv(p + 3); acc += m3;
        }
    };
    // gather one group's 4 h16 rows into named registers (LDS src broadcast)
    auto ld4 = [&](int g, _Float16& x0, _Float16& x1, _Float16& x2, _Float16& x3) {
        const int4 s = *(const int4*)&sSRC[wv][g*4];
        x0 = h16[(unsigned)(s.x << 6) + lane];
        x1 = h16[(unsigned)(s.y << 6) + lane];
        x2 = h16[(unsigned)(s.z << 6) + lane];
        x3 = h16[(unsigned)(s.w << 6) + lane];
    };

    // register prefetch of the first chunk (ea/src payload)
    uint4 rA = uint4{0,0,0,0}, rB = uint4{0,0,0,0};
    int   rS = 0;
    if (e0 < eEnd) {
        const int cnt0 = min(64, eEnd - e0);
        if (lane < 2*cnt0)      rA = csr_ea[(size_t)e0*2 + lane];
        if (64 + lane < 2*cnt0) rB = csr_ea[(size_t)e0*2 + 64 + lane];
        if (lane < cnt0)        rS = csr_src[e0 + lane];
    }

    for (int base = e0; base < eEnd; base += 64) {
        const int cnt = min(64, eEnd - base);
        // write staged regs to LDS (wave-local, no barrier needed)
        sEAw[lane]      = rA;
        sEAw[64 + lane] = rB;
        sSRC[wv][lane]  = rS;
        // issue NEXT chunk's global loads now — latency hides under compute
        const int nbase = base + 64;
        if (nbase < eEnd) {
            const int ncnt = min(64, eEnd - nbase);
            if (lane < 2*ncnt)      rA = csr_ea[(size_t)nbase*2 + lane];
            if (64 + lane < 2*ncnt) rB = csr_ea[(size_t)nbase*2 + 64 + lane];
            if (lane < ncnt)        rS = csr_src[nbase + lane];
        }

        const int grpN = cnt >> 2;
        if (grpN) {
            // 4-deep pipeline: buffers a (consume), b, c, d (fill 3 ahead)
            _Float16 a0,a1,a2,a3, b0,b1,b2,b3, c0,c1,c2,c3, d0,d1,d2,d3;
            ld4(0, a0,a1,a2,a3);
            ld4(grpN > 1 ? 1 : grpN-1, b0,b1,b2,b3);
            ld4(grpN > 2 ? 2 : grpN-1, c0,c1,c2,c3);
            #pragma unroll 1
            for (int gp = 0; gp < grpN; ++gp) {
                const int gn = (gp + 3 < grpN) ? gp + 3 : grpN - 1;
                ld4(gn, d0,d1,d2,d3);
                doGroup(sEAw + gp*8, base + gp*4,
                        (float)a0, (float)a1, (float)a2, (float)a3);
                a0=b0; a1=b1; a2=b2; a3=b3;      // rotate (static names)
                b0=c0; b1=c1; b2=c2; b3=c3;
                c0=d0; c1=d1; c2=d2; c3=d3;
            }
        }
        for (int k = grpN*4; k < cnt; ++k) {         // chunk tail (0-3 edges)
            const int p = base + k;
            const int sv = sSRC[wv][k];
            const float hv = (float)h16[(unsigned)(sv << 6) + lane];
            uint4 A = sEAw[k*2], B = sEAw[k*2 + 1];
            const float m = msg(A, B, hv);
            if (p >= nb) adv(p);
            acc += m;
        }
    }
    if (e0 < eEnd)                                   // final node flush
        tileW[(cur - nwb)*72 + lane] = (_Float16)acc;

    // ---------------- MFMA phase (mlp1) — no barrier: own rows only -------
    const int li = lane & 15, quad = lane >> 4;
    const int rb = n0 + nwb;
    const bool active = (rb < NN);                   // NN % 16 == 0

    v8h Bf[8];
    #pragma unroll
    for (int i = 0; i < 8; ++i) Bf[i] = Wpk[i*64 + lane];

    v4f accm[4] = {v4f{0,0,0,0}, v4f{0,0,0,0}, v4f{0,0,0,0}, v4f{0,0,0,0}};
    if (active) {
        const _Float16* trow = tileW + li*72 + quad*8;
        v8h Af0 = *(const v8h*)(trow);
        v8h Af1 = *(const v8h*)(trow + 32);
        const size_t off = (size_t)(rb + li)*64 + quad*8;
        Af0 += *(const v8h*)(h16 + off);             // self term "+h"
        Af1 += *(const v8h*)(h16 + off + 32);
        #pragma unroll
        for (int t = 0; t < 4; ++t) {
            accm[t] = __builtin_amdgcn_mfma_f32_16x16x32_f16(Af0, Bf[t*2+0], accm[t], 0, 0, 0);
            accm[t] = __builtin_amdgcn_mfma_f32_16x16x32_f16(Af1, Bf[t*2+1], accm[t], 0, 0, 0);
        }
    }

    float ps[4] = {0.f, 0.f, 0.f, 0.f}, pq[4] = {0.f, 0.f, 0.f, 0.f};
    if (active) {
        #pragma unroll
        for (int t = 0; t < 4; ++t) {
            const int col = li + 16*t;
            const float bcol = bias[col];
            #pragma unroll
            for (int r = 0; r < 4; ++r) {
                const int row = rb + quad*4 + r;
                float v = accm[t][r] + bcol;
                ps[t] += v; pq[t] += v*v;            // BN stats on fp32 value
                t16[(size_t)row*64 + col] = (_Float16)v;
            }
        }
    }

    // BN partial reduction: sEA[wv] reused as per-wave sS(256f)+sQ(256f)
    float* sSw = (float*)sEA[wv];
    #pragma unroll
    for (int t = 0; t < 4; ++t) {
        sSw[lane*4 + t]       = ps[t];
        sSw[256 + lane*4 + t] = pq[t];
    }
    __syncthreads();
    if (tid < 64) {
        const int t = tid >> 4, li2 = tid & 15;
        float s = 0.f, q = 0.f;
        #pragma unroll
        for (int w = 0; w < 4; ++w) {
            const float* pS = (const float*)sEA[w];
            #pragma unroll
            for (int qd = 0; qd < 4; ++qd) {
                const int idx = (qd*16 + li2)*4 + t;
                s += pS[idx]; q += pS[256 + idx];
            }
        }
        atomicAdd(bn_sum + tid, s);
        atomicAdd(bn_sumsq + tid, q);
    }
}

// ---------------------------------------------------------------------------
// MFMA node GEMM: [NN,64] @ [64,64] + bias.
// IN_MODE 0: A = fp32 raw (in0). IN_MODE 2: A = relu(bn(f16 in16)) with
// scale/shift computed inline from raw BN sums.
// OUT_HALF stores f16; OUT_POOL atomically accumulates relu(v) into
// pooled[batch[row]] (wave-level shfl reduction on the sorted-batch fast path).
template<int IN_MODE, bool OUT_RELU, bool OUT_HALF, bool OUT_POOL>
__global__ __launch_bounds__(256) void mfma_gemm_kernel(
    const float* __restrict__ in0, const _Float16* __restrict__ in16,
    const v8h* __restrict__ Wpk, const float* __restrict__ bias,
    const float* __restrict__ bni_sum, const float* __restrict__ bni_sumsq,
    const float* __restrict__ bni_g, const float* __restrict__ bni_b,
    float bni_invc,
    _Float16* __restrict__ out16,
    const int* __restrict__ batch, float* __restrict__ pooled)
{
    __shared__ float sSc[64], sSh[64];
    const int tid = threadIdx.x;
    const int wv = tid >> 6, l = tid & 63;
    const int li = l & 15, quad = l >> 4;
    const int rb = (blockIdx.x * 4 + wv) * 16;   // row-block base
    const bool active = (rb < NN);               // NN % 16 == 0

    if constexpr (IN_MODE == 2) {
        if (tid < 64)
            bn_sc_sh(bni_sum[tid], bni_sumsq[tid], bni_g[tid], bni_b[tid],
                     bni_invc, sSc[tid], sSh[tid]);
        __syncthreads();
    }

    v8h Bf[8];
    #pragma unroll
    for (int i = 0; i < 8; ++i) Bf[i] = Wpk[i*64 + l];

    v4f acc[4] = {v4f{0,0,0,0}, v4f{0,0,0,0}, v4f{0,0,0,0}, v4f{0,0,0,0}};

    if (active) {
        v8h Af[2];
        if constexpr (IN_MODE == 2) {
            const _Float16* arow = in16 + (size_t)(rb + li)*64 + quad*8;
            v8h r0 = *(const v8h*)(arow);
            v8h r1 = *(const v8h*)(arow + 32);
            v8h a0, a1;
            #pragma unroll
            for (int j = 0; j < 8; ++j) {
                const int k0 = quad*8 + j;
                const int k1 = 32 + quad*8 + j;
                a0[j] = (_Float16)fmaxf(fmaf((float)r0[j], sSc[k0], sSh[k0]), 0.f);
                a1[j] = (_Float16)fmaxf(fmaf((float)r1[j], sSc[k1], sSh[k1]), 0.f);
            }
            Af[0] = a0; Af[1] = a1;
        } else {
            const float* arow = in0 + (size_t)(rb + li)*64 + quad*8;
            #pragma unroll
            for (int f = 0; f < 2; ++f) {
                float4 x0 = *(const float4*)(arow + f*32);
                float4 x1 = *(const float4*)(arow + f*32 + 4);
                v8h a;
                a[0] = (_Float16)x0.x; a[1] = (_Float16)x0.y;
                a[2] = (_Float16)x0.z; a[3] = (_Float16)x0.w;
                a[4] = (_Float16)x1.x; a[5] = (_Float16)x1.y;
                a[6] = (_Float16)x1.z; a[7] = (_Float16)x1.w;
                Af[f] = a;
            }
        }
        #pragma unroll
        for (int t = 0; t < 4; ++t) {
            acc[t] = __builtin_amdgcn_mfma_f32_16x16x32_f16(Af[0], Bf[t*2+0], acc[t], 0, 0, 0);
            acc[t] = __builtin_amdgcn_mfma_f32_16x16x32_f16(Af[1], Bf[t*2+1], acc[t], 0, 0, 0);
        }
    }

    if constexpr (OUT_HALF) {
        if (active) {
            #pragma unroll
            for (int t = 0; t < 4; ++t) {
                const int col = li + 16*t;
                const float bcol = bias[col];
                #pragma unroll
                for (int r = 0; r < 4; ++r) {
                    const int row = rb + quad*4 + r;
                    float v = acc[t][r] + bcol;
                    if constexpr (OUT_RELU) v = fmaxf(v, 0.f);
                    out16[(size_t)row*64 + col] = (_Float16)v;
                }
            }
        }
    }

    if constexpr (OUT_POOL) {
        if (active) {
            const int b0  = batch[rb];
            const int b15 = batch[rb + 15];
            if (b0 == b15) {            // whole wave's 16 rows in one graph
                #pragma unroll
                for (int t = 0; t < 4; ++t) {
                    const int col = li + 16*t;
                    const float bcol = bias[col];
                    float s = 0.f;
                    #pragma unroll
                    for (int r = 0; r < 4; ++r)
                        s += fmaxf(acc[t][r] + bcol, 0.f);
                    s += __shfl_xor(s, 16);
                    s += __shfl_xor(s, 32);
                    if (quad == 0) atomicAdd(&pooled[b0*64 + col], s);
                }
            } else {                    // rare straddling wave: per-row
                #pragma unroll
                for (int t = 0; t < 4; ++t) {
                    const int col = li + 16*t;
                    const float bcol = bias[col];
                    #pragma unroll
                    for (int r = 0; r < 4; ++r) {
                        const int row = rb + quad*4 + r;
                        const float v = fmaxf(acc[t][r] + bcol, 0.f);
                        atomicAdd(&pooled[batch[row]*64 + col], v);
                    }
                }
            }
        }
    }
}

// ---------------------------------------------------------------------------
// small vector GEMM for the 512-row head.
// IN_MODE==2 applies relu(bn(x)) during load; scale/shift inline from raw sums.
template<int IN_MODE, bool OUT_RELU, bool OUT_ACCUM>
__global__ __launch_bounds__(256) void gemm64_kernel(
    const float* __restrict__ in0,
    const float* __restrict__ W, const float* __restrict__ bias,
    const float* __restrict__ bni_sum, const float* __restrict__ bni_sumsq,
    const float* __restrict__ bni_g, const float* __restrict__ bni_b,
    float bni_invc,
    float* __restrict__ out, int nrows,
    float* __restrict__ bn_sum, float* __restrict__ bn_sumsq)
{
    __shared__ __align__(16) float sIn[64*64];
    __shared__ float sRedS[512];
    __shared__ float sRedQ[512];
    __shared__ __align__(16) float sSc[64], sSh[64];
    const int tid = threadIdx.x;
    const int c  = tid & 31;
    const int rg = tid >> 5;
    const int r0 = blockIdx.x * 64;

    if constexpr (IN_MODE == 2) {
        if (tid < 64)
            bn_sc_sh(bni_sum[tid], bni_sumsq[tid], bni_g[tid], bni_b[tid],
                     bni_invc, sSc[tid], sSh[tid]);
        __syncthreads();
    }

    float w0[64], w1[64];
    #pragma unroll
    for (int k = 0; k < 64; ++k) { w0[k] = W[k*64 + c]; w1[k] = W[k*64 + c + 32]; }
    const float b0 = bias[c], b1 = bias[c + 32];

    for (int i = tid; i < 1024; i += 256) {
        const int r  = i >> 4;
        const int c4 = (i & 15) * 4;
        const int gr = r0 + r;
        float4 v = make_float4(0.f, 0.f, 0.f, 0.f);
        if (gr < nrows) {
            v = *(const float4*)(in0 + (size_t)gr*64 + c4);
            if constexpr (IN_MODE == 2) {
                float4 s4 = *(const float4*)(sSc + c4);
                float4 h4 = *(const float4*)(sSh + c4);
                v.x = fmaxf(fmaf(v.x, s4.x, h4.x), 0.f);
                v.y = fmaxf(fmaf(v.y, s4.y, h4.y), 0.f);
                v.z = fmaxf(fmaf(v.z, s4.z, h4.z), 0.f);
                v.w = fmaxf(fmaf(v.w, s4.w, h4.w), 0.f);
            }
        }
        *(float4*)(sIn + r*64 + c4) = v;
    }
    __syncthreads();

    float ps0 = 0.f, psq0 = 0.f, ps1 = 0.f, psq1 = 0.f;
    #pragma unroll
    for (int i = 0; i < 8; ++i) {
        const int r = rg + 8*i;
        float a0 = b0, a1 = b1;
        #pragma unroll
        for (int k = 0; k < 64; k += 4) {
            float4 a = *(const float4*)(sIn + r*64 + k);
            a0 = fmaf(a.x, w0[k+0], a0); a1 = fmaf(a.x, w1[k+0], a1);
            a0 = fmaf(a.y, w0[k+1], a0); a1 = fmaf(a.y, w1[k+1], a1);
            a0 = fmaf(a.z, w0[k+2], a0); a1 = fmaf(a.z, w1[k+2], a1);
            a0 = fmaf(a.w, w0[k+3], a0); a1 = fmaf(a.w, w1[k+3], a1);
        }
        const int gr = r0 + r;
        if (gr < nrows) {
            if constexpr (OUT_ACCUM) {
                ps0 += a0; psq0 += a0*a0;
                ps1 += a1; psq1 += a1*a1;
            }
            out[(size_t)gr*64 + c]      = OUT_RELU ? fmaxf(a0, 0.f) : a0;
            out[(size_t)gr*64 + c + 32] = OUT_RELU ? fmaxf(a1, 0.f) : a1;
        }
    }

    if constexpr (OUT_ACCUM) {
        sRedS[rg*64 + c]      = ps0;
        sRedS[rg*64 + c + 32] = ps1;
        sRedQ[rg*64 + c]      = psq0;
        sRedQ[rg*64 + c + 32] = psq1;
        __syncthreads();
        if (tid < 64) {
            float s = 0.f, q = 0.f;
            #pragma unroll
            for (int g = 0; g < 8; ++g) { s += sRedS[g*64 + tid]; q += sRedQ[g*64 + tid]; }
            atomicAdd(bn_sum + tid, s);
            atomicAdd(bn_sumsq + tid, q);
        }
    }
}

// ---------------------------------------------------------------------------
// final head: out = bn(hb) @ fo3_w + fo3_b, BN inline from raw sums
__global__ __launch_bounds__(256) void head_final_kernel(
    const float* __restrict__ hb,
    const float* __restrict__ bni_sum, const float* __restrict__ bni_sumsq,
    const float* __restrict__ bni_g, const float* __restrict__ bni_b,
    float bni_invc,
    const float* __restrict__ fo3_w, const float* __restrict__ fo3_b,
    float* __restrict__ out)
{
    __shared__ float sSc[64], sSh[64];
    const int tid = threadIdx.x;
    if (tid < 64)
        bn_sc_sh(bni_sum[tid], bni_sumsq[tid], bni_g[tid], bni_b[tid],
                 bni_invc, sSc[tid], sSh[tid]);
    __syncthreads();
    const int idx = blockIdx.x * 256 + tid;
    if (idx >= NG * NC) return;
    const int g = idx / NC, c = idx % NC;
    float acc = fo3_b[c];
    for (int k = 0; k < 64; ++k) {
        float v = fmaf(hb[g*64 + k], sSc[k], sSh[k]);
        acc = fmaf(v, fo3_w[k*NC + c], acc);
    }
    out[idx] = acc;
}

// ---------------------------------------------------------------------------
extern "C" void kernel_launch(void* const* d_in, const int* in_sizes, int n_in,
                              void* d_out, int out_size, void* d_ws, size_t ws_size,
                              hipStream_t stream) {
    const float* x         = (const float*)d_in[0];
    const int*   edge_index= (const int*)  d_in[1];
    const int*   batch     = (const int*)  d_in[2];
    const float* edge_attr = (const float*)d_in[3];
    const float* w_node    = (const float*)d_in[4];
    const float* b_node    = (const float*)d_in[5];
    const float* w_edge    = (const float*)d_in[6];
    const float* b_edge    = (const float*)d_in[7];
    const float* lin_w     = (const float*)d_in[8];
    const float* lin_b     = (const float*)d_in[9];
    const float* mlp1_w    = (const float*)d_in[10];
    const float* mlp1_b    = (const float*)d_in[11];
    const float* bn1_g     = (const float*)d_in[12];
    const float* bn1_b     = (const float*)d_in[13];
    const float* mlp2_w    = (const float*)d_in[14];
    const float* mlp2_b    = (const float*)d_in[15];
    const float* fo1_w     = (const float*)d_in[16];
    const float* fo1_b     = (const float*)d_in[17];
    const float* fo_bn1_g  = (const float*)d_in[18];
    const float* fo_bn1_b  = (const float*)d_in[19];
    const float* fo2_w     = (const float*)d_in[20];
    const float* fo2_b     = (const float*)d_in[21];
    const float* fo_bn2_g  = (const float*)d_in[22];
    const float* fo_bn2_b  = (const float*)d_in[23];
    const float* fo3_w     = (const float*)d_in[24];
    const float* fo3_b     = (const float*)d_in[25];
    float* out = (float*)d_out;

    char* ws = (char*)d_ws;
    _Float16* t16 = (_Float16*)(ws);               // 12.8 MB (CSR-build ints alias)
    int* counts = (int*)ws;                        // NN ints (dead before t16 written)
    int* next   = (int*)ws + NN;                   // NN ints (dead after scatter)
    int*   csr_src = (int*)(ws + 25600000);        // 4.8 MB
    uint4* csr_ea  = (uint4*)(ws + 30400000);      // 38.4 MB
    int* rowptr = (int*)(ws + 68800000);           // NN+1 ints
    _Float16* h16   = (_Float16*)(ws + 69300000);  // 12.8 MB
    float* sm   = (float*)(ws + 94900000);
    unsigned* Wc16 = (unsigned*)sm;  // 3*512 uints (edge weights f16)
    float* bc       = sm + 1536;     // 192
    float* bnbuf    = sm + 1728;     // 5 pairs x 128 floats (sum at +0, sumsq at +64)
    float* pooled   = sm + 2368;     // 32768
    float* ha       = sm + 35136;    // 32768
    float* hb       = sm + 67904;    // 32768
    int* bsum       = (int*)(sm + 100672);   // 512 ints
    int* bscan      = bsum + 512;            // 512 ints
    v8h* Wpk        = (v8h*)(sm + 101696);   // 7*512*16 B (16B-aligned)

    const int* src = edge_index;
    const int* dst = edge_index + NE;

    const int mfma_blocks  = (NN/16 + 3) / 4;    // 1563
    const int edge_blocks  = (NE + 255) / 256;   // 4688

    prep_kernel<<<NL, 1024, 0, stream>>>(w_edge, b_edge, lin_w, lin_b, Wc16, bc);
    pack_w_kernel<<<7, 512, 0, stream>>>(w_node, mlp1_w, mlp2_w, Wpk);

    // h16 = f16( x @ w_node + b_node )
    mfma_gemm_kernel<0, false, true, false><<<mfma_blocks, 256, 0, stream>>>(
        x, nullptr, Wpk, b_node,
        nullptr, nullptr, nullptr, nullptr, 0.f,
        h16, nullptr, nullptr);

    // CSR build (per launch; edge_index is an input)
    hipMemsetAsync(counts, 0, NN * sizeof(int), stream);
    // zero all 5 BN-stat pairs + pooled in ONE memset (contiguous region)
    hipMemsetAsync(bnbuf, 0, (640 + 32768) * sizeof(float), stream);
    hist_kernel<<<edge_blocks, 256, 0, stream>>>(dst, counts);
    scan_reduce_kernel<<<NB_SCAN, 256, 0, stream>>>(counts, bsum);
    scan_partials_kernel<<<1, 512, 0, stream>>>(bsum, bscan);
    scan_final_kernel<<<NB_SCAN, 256, 0, stream>>>(counts, bscan, rowptr, next);
    scatter_kernel<<<edge_blocks, 256, 0, stream>>>(
        src, dst, edge_attr, next, csr_src, csr_ea);

    for (int l = 0; l < NL; ++l) {
        float* bnL = bnbuf + l * 128;
        // fused: t16 = ( segsum(relu(ea@Wc + h[src])) + h ) @ mlp1_w + b, + BN stats
        agg_mlp1_kernel<<<NBLK, 256, 0, stream>>>(
            rowptr, csr_src, csr_ea, Wc16 + l*512, bc + l*64, h16,
            Wpk + (1+l)*512, mlp1_b + l*64, t16, bnL, bnL + 64);
        if (l < NL - 1) {
            // h16 = f16( relu( relu(bn(t16)) @ mlp2_w + b ) )
            mfma_gemm_kernel<2, true, true, false><<<mfma_blocks, 256, 0, stream>>>(
                nullptr, t16, Wpk + (4+l)*512, mlp2_b + l*64,
                bnL, bnL + 64, bn1_g + l*64, bn1_b + l*64, 1.0f / NN,
                h16, nullptr, nullptr);
        } else {
            // last layer: skip h16 store; pool relu(...) directly into pooled
            mfma_gemm_kernel<2, false, false, true><<<mfma_blocks, 256, 0, stream>>>(
                nullptr, t16, Wpk + (4+l)*512, mlp2_b + l*64,
                bnL, bnL + 64, bn1_g + l*64, bn1_b + l*64, 1.0f / NN,
                nullptr, batch, pooled);
        }
    }

    float* bnH1 = bnbuf + 3 * 128;
    float* bnH2 = bnbuf + 4 * 128;
    gemm64_kernel<0, false, true><<<NG/64, 256, 0, stream>>>(
        pooled, fo1_w, fo1_b,
        nullptr, nullptr, nullptr, nullptr, 0.f,
        ha, NG, bnH1, bnH1 + 64);
    gemm64_kernel<2, false, true><<<NG/64, 256, 0, stream>>>(
        ha, fo2_w, fo2_b,
        bnH1, bnH1 + 64, fo_bn1_g, fo_bn1_b, 1.0f / NG,
        hb, NG, bnH2, bnH2 + 64);
    head_final_kernel<<<(NG*NC + 255)/256, 256, 0, stream>>>(
        hb, bnH2, bnH2 + 64, fo_bn2_g, fo_bn2_b, 1.0f / NG,
        fo3_w, fo3_b, out);
}